// Round 8
// baseline (890.409 us; speedup 1.0000x reference)
//
#include <hip/hip_runtime.h>
#include <hip/hip_bf16.h>

#define DD   128
#define HH   8

typedef short bf16x8 __attribute__((ext_vector_type(8)));
typedef float f32x4  __attribute__((ext_vector_type(4)));

__device__ __forceinline__ float b2f(unsigned short v){
  union { unsigned int u; float f; } x; x.u = ((unsigned int)v) << 16; return x.f;
}
__device__ __forceinline__ unsigned short f2b(float f){
  __hip_bfloat16 h = __float2bfloat16(f);
  return *(unsigned short*)&h;
}
struct __align__(8) us4 { unsigned short x,y,z,w; };
struct __align__(4) us2 { unsigned short x,y; };

__device__ __forceinline__ float gld(const void* p, size_t i, bool f32){
  if (f32) return ((const float*)p)[i];
  return b2f(((const unsigned short*)p)[i]);
}

// Detect input float dtype. emb ~ N(0,1)*0.05. If f32, odd ushorts are mantissa
// garbage -> huge "bf16" values. flag=1 -> inputs are f32.
__global__ __launch_bounds__(64) void k_detect(const unsigned short* __restrict__ emb,
                                               int* __restrict__ flag){
  int t = threadIdx.x;
  float m = 0.f;
  for (int i=t; i<128; i+=64){
    float x = fabsf(b2f(emb[i]));
    if (x < 1e30f) m = fmaxf(m, x);
  }
#pragma unroll
  for (int s=1;s<64;s<<=1) m = fmaxf(m, __shfl_xor(m, s, 64));
  if (t==0) *flag = (m > 1e4f) ? 1 : 0;
}

// All 8 weight blocks -> bf16 TRANSPOSED staging ([n][k]) in one launch.
struct WPtrs { const void* p[8]; };
__global__ __launch_bounds__(256) void w_repack8(
    WPtrs W, unsigned short* __restrict__ stage,
    size_t bo, const int* __restrict__ dflag)
{
  const bool wf32 = (*dflag) != 0;
  int mat = blockIdx.x >> 6;
  int i = (blockIdx.x & 63)*256 + threadIdx.x;
  int k = i >> 7, n = i & 127;
  float x;
  if (wf32) x = ((const float*)W.p[mat])[bo + i];
  else      x = b2f(((const unsigned short*)W.p[mat])[bo + i]);
  stage[(size_t)mat*DD*DD + n*DD + k] = f2b(x);
}

enum { EPI_STORE=0, EPI_SCALE_CONST=1, EPI_SCALE_GATHER=2, EPI_RELU=3, EPI_RELU_RES=4 };

#define APAD 136   // 128 + 8 bf16: breaks stride-256B bank aliasing
#define CPAD 132   // f32 row pad for epilogue repack

// C[M,128] = epi( prologue(A)[M,128] @ B[128,128] ), B bf16 TRANSPOSED ([n][k]).
// MFMA 16x16x32 bf16. Block: 256 thr = 4 waves; 64 rows x 128 cols per block.
template<int EPI, bool NORM, bool INB, bool OUTB>
__global__ __launch_bounds__(256) void gemm128m(
    const void* __restrict__ Av, const unsigned short* __restrict__ Bt,
    void* __restrict__ Cv, int M,
    const float* __restrict__ z, const float* __restrict__ svec,
    const float* __restrict__ P2, const int* __restrict__ gidx,
    const unsigned short* __restrict__ Rb)
{
  __shared__ unsigned short Asb[64*APAD];    // [row][k] bf16
  __shared__ unsigned short Btb[128*APAD];   // [n][k] bf16; aliased by C f32 later
  const int tid = threadIdx.x;
  const int wave = tid >> 6, lane = tid & 63;
  const int row0 = blockIdx.x * 64;

  {
    int r = tid >> 2, cb = (tid & 3) * 32;
    int gr = row0 + r;
    if (INB){
      const unsigned short* Ab = (const unsigned short*)Av;
#pragma unroll
      for (int j=0;j<4;j++){
        int c = cb + j*8;
        uint4 raw = make_uint4(0,0,0,0);
        if (gr < M) raw = *(const uint4*)(Ab + (size_t)gr*DD + c);
        *(uint4*)&Asb[r*APAD + c] = raw;
      }
    } else {
      const float* Af = (const float*)Av;
#pragma unroll
      for (int j=0;j<8;j++){
        int c = cb + j*4;
        float4 val = make_float4(0.f,0.f,0.f,0.f);
        if (gr < M){
          val = *(const float4*)(Af + (size_t)gr*DD + c);
          if (NORM){
            float s = 1.0f / (z[(size_t)gr*HH + (c>>4)] + 1e-9f);
            val.x*=s; val.y*=s; val.z*=s; val.w*=s;
          }
        }
        us4 o; o.x=f2b(val.x); o.y=f2b(val.y); o.z=f2b(val.z); o.w=f2b(val.w);
        *(us4*)&Asb[r*APAD + c] = o;
      }
    }
  }
  {
    int n = tid >> 1, k0s = (tid & 1) * 64;
#pragma unroll
    for (int j=0;j<8;j++){
      uint4 raw = *(const uint4*)(Bt + (size_t)n*DD + k0s + j*8);
      *(uint4*)&Btb[n*APAD + k0s + j*8] = raw;
    }
  }
  __syncthreads();

  f32x4 acc[8];
#pragma unroll
  for (int t=0;t<8;t++) acc[t] = (f32x4){0.f,0.f,0.f,0.f};
  const int am = (lane & 15), kq = (lane >> 4) * 8;
#pragma unroll
  for (int k0=0;k0<128;k0+=32){
    bf16x8 a = *(bf16x8*)&Asb[(wave*16 + am)*APAD + k0 + kq];
#pragma unroll
    for (int t=0;t<8;t++){
      bf16x8 b = *(bf16x8*)&Btb[(t*16 + am)*APAD + k0 + kq];
      acc[t] = __builtin_amdgcn_mfma_f32_16x16x32_bf16(a, b, acc[t], 0,0,0);
    }
  }
  __syncthreads();
  float* Cls = (float*)Btb;   // [64][CPAD] f32
  {
    int rr = wave*16 + (lane>>4)*4;
    int cc = lane & 15;
#pragma unroll
    for (int t=0;t<8;t++)
#pragma unroll
      for (int r=0;r<4;r++)
        Cls[(rr + r)*CPAD + t*16 + cc] = acc[t][r];
  }
  __syncthreads();

  {
    int r = tid >> 2, cb = (tid & 3) * 32;
    int gr = row0 + r;
    if (gr < M){
#pragma unroll
      for (int j=0;j<8;j++){
        int c = cb + j*4;
        float4 o = *(float4*)&Cls[r*CPAD + c];
        if (EPI == EPI_SCALE_CONST){
          o.x*=svec[c+0]; o.y*=svec[c+1]; o.z*=svec[c+2]; o.w*=svec[c+3];
        } else if (EPI == EPI_SCALE_GATHER){
          int g = gidx[gr];
          const float* p = P2 + (size_t)g*DD + c;
          o.x*=(svec[c+0]+p[0]); o.y*=(svec[c+1]+p[1]);
          o.z*=(svec[c+2]+p[2]); o.w*=(svec[c+3]+p[3]);
        } else if (EPI == EPI_RELU){
          o.x=fmaxf(o.x,0.f); o.y=fmaxf(o.y,0.f); o.z=fmaxf(o.z,0.f); o.w=fmaxf(o.w,0.f);
        } else if (EPI == EPI_RELU_RES){
          us4 rb = *(const us4*)(Rb + (size_t)gr*DD + c);
          o.x=fmaxf(o.x,0.f)+b2f(rb.x); o.y=fmaxf(o.y,0.f)+b2f(rb.y);
          o.z=fmaxf(o.z,0.f)+b2f(rb.z); o.w=fmaxf(o.w,0.f)+b2f(rb.w);
        }
        if (OUTB){
          us4 ob; ob.x=f2b(o.x); ob.y=f2b(o.y); ob.z=f2b(o.z); ob.w=f2b(o.w);
          *(us4*)((unsigned short*)Cv + (size_t)gr*DD + c) = ob;
        } else {
          *(float4*)((float*)Cv + (size_t)gr*DD + c) = o;
        }
      }
    }
  }
}

// Fused Q/K/V gemm: stage A once, run 3 weight matrices through the same LDS.
template<int EPIQ, bool INB>
__global__ __launch_bounds__(256) void gemm_qkv(
    const void* __restrict__ Av,
    const unsigned short* __restrict__ Btq, const unsigned short* __restrict__ Btk,
    const unsigned short* __restrict__ Btv,
    unsigned short* __restrict__ Cq, unsigned short* __restrict__ Ck,
    unsigned short* __restrict__ Cvo, int M,
    const float* __restrict__ svec, const float* __restrict__ P2,
    const int* __restrict__ gidx)
{
  __shared__ unsigned short Asb[64*APAD];
  __shared__ unsigned short Btb[128*APAD];
  const int tid = threadIdx.x;
  const int wave = tid >> 6, lane = tid & 63;
  const int row0 = blockIdx.x * 64;

  {
    int r = tid >> 2, cb = (tid & 3) * 32;
    int gr = row0 + r;
    if (INB){
      const unsigned short* Ab = (const unsigned short*)Av;
#pragma unroll
      for (int j=0;j<4;j++){
        int c = cb + j*8;
        uint4 raw = make_uint4(0,0,0,0);
        if (gr < M) raw = *(const uint4*)(Ab + (size_t)gr*DD + c);
        *(uint4*)&Asb[r*APAD + c] = raw;
      }
    } else {
      const float* Af = (const float*)Av;
#pragma unroll
      for (int j=0;j<8;j++){
        int c = cb + j*4;
        float4 val = make_float4(0.f,0.f,0.f,0.f);
        if (gr < M) val = *(const float4*)(Af + (size_t)gr*DD + c);
        us4 o; o.x=f2b(val.x); o.y=f2b(val.y); o.z=f2b(val.z); o.w=f2b(val.w);
        *(us4*)&Asb[r*APAD + c] = o;
      }
    }
  }

  const unsigned short* Bts[3] = {Btq, Btk, Btv};
  unsigned short* Cs[3] = {Cq, Ck, Cvo};
  const int am = (lane & 15), kq = (lane >> 4) * 8;

  for (int ph=0; ph<3; ph++){
    {
      int n = tid >> 1, k0s = (tid & 1) * 64;
      const unsigned short* Bt = Bts[ph];
#pragma unroll
      for (int j=0;j<8;j++){
        uint4 raw = *(const uint4*)(Bt + (size_t)n*DD + k0s + j*8);
        *(uint4*)&Btb[n*APAD + k0s + j*8] = raw;
      }
    }
    __syncthreads();
    f32x4 acc[8];
#pragma unroll
    for (int t=0;t<8;t++) acc[t] = (f32x4){0.f,0.f,0.f,0.f};
#pragma unroll
    for (int k0=0;k0<128;k0+=32){
      bf16x8 a = *(bf16x8*)&Asb[(wave*16 + am)*APAD + k0 + kq];
#pragma unroll
      for (int t=0;t<8;t++){
        bf16x8 b = *(bf16x8*)&Btb[(t*16 + am)*APAD + k0 + kq];
        acc[t] = __builtin_amdgcn_mfma_f32_16x16x32_bf16(a, b, acc[t], 0,0,0);
      }
    }
    __syncthreads();
    float* Cls = (float*)Btb;
    {
      int rr = wave*16 + (lane>>4)*4;
      int cc = lane & 15;
#pragma unroll
      for (int t=0;t<8;t++)
#pragma unroll
        for (int r=0;r<4;r++)
          Cls[(rr + r)*CPAD + t*16 + cc] = acc[t][r];
    }
    __syncthreads();
    {
      int r = tid >> 2, cb = (tid & 3) * 32;
      int gr = row0 + r;
      if (gr < M){
#pragma unroll
        for (int j=0;j<8;j++){
          int c = cb + j*4;
          float4 o = *(float4*)&Cls[r*CPAD + c];
          if (ph == 0){
            if (EPIQ == EPI_SCALE_GATHER){
              int g = gidx[gr];
              const float* p = P2 + (size_t)g*DD + c;
              o.x*=(svec[c+0]+p[0]); o.y*=(svec[c+1]+p[1]);
              o.z*=(svec[c+2]+p[2]); o.w*=(svec[c+3]+p[3]);
            } else { // SCALE_CONST
              o.x*=svec[c+0]; o.y*=svec[c+1]; o.z*=svec[c+2]; o.w*=svec[c+3];
            }
          }
          us4 ob; ob.x=f2b(o.x); ob.y=f2b(o.y); ob.z=f2b(o.z); ob.w=f2b(o.w);
          *(us4*)(Cs[ph] + (size_t)gr*DD + c) = ob;
        }
      }
    }
    __syncthreads();
  }
}

// Static param-name graph -> base params. base: [0..7]=tw,[8..15]=n1,[16..23]=e1,
// [24..151]=n2,[152..279]=e2
__global__ __launch_bounds__(256) void k_static(
    const void* __restrict__ emb, const int* __restrict__ svals,
    const int* __restrict__ ssrc, const int* __restrict__ sdst,
    const void* __restrict__ u, const void* __restrict__ W2,
    const void* __restrict__ W1, float* __restrict__ base, int nsrc,
    const int* __restrict__ dflag)
{
  __shared__ float sagg[15][128];
  __shared__ float ssc[15][16];
  __shared__ float sww[15][16];
  const bool wf32 = (*dflag) != 0;
  const int t = threadIdx.x;
  for (int i=t;i<15*128;i+=256) ((float*)sagg)[i]=0.f;
  __syncthreads();
  if (t < 128){
    for (int i=0;i<nsrc;i++){
      int row = sdst[i]; int vr = svals[ssrc[i]];
      sagg[row][t] += gld(emb, (size_t)vr*DD + t, wf32);
    }
  }
  __syncthreads();
  if (t < 240){
    int n = t>>4, l = t&15;
    float a=0.f;
    for (int d=0;d<128;d++) a += sagg[n][d]*gld(u, l*128+d, wf32);
    ssc[n][l] = a * 0.08838834764831845f;
  }
  __syncthreads();
  if (t < 15){
    float mx=-1e30f;
    for (int l=0;l<16;l++) mx = fmaxf(mx, ssc[t][l]);
    float s=0.f;
    for (int l=0;l<16;l++){ float e=__expf(ssc[t][l]-mx); sww[t][l]=e; s+=e; }
    float inv = 1.f/s;
    for (int l=0;l<16;l++) sww[t][l]*=inv;
  }
  __syncthreads();
  if (t < 8){
    float a=0.f,b=0.f,c=0.f;
    for (int l=0;l<16;l++){
      float wv = gld(W1, l*8+t, wf32);
      a += sww[0][l]*wv; b += sww[3][l]*wv; c += sww[9][l]*wv;
    }
    base[t]=a; base[8+t]=b; base[16+t]=c;
  }
  if (t < 128){
    float a=0.f,b=0.f;
    for (int l=0;l<16;l++){
      float wv = gld(W2, l*128+t, wf32);
      a += sww[6][l]*wv; b += sww[12][l]*wv;
    }
    base[24+t]=a; base[152+t]=b;
  }
}

template<bool OUTB>
__global__ __launch_bounds__(256) void gather_rows(
    const void* __restrict__ emb, const int* __restrict__ vals,
    void* __restrict__ dstv, int n, const int* __restrict__ dflag)
{
  const bool wf32 = (*dflag) != 0;
  int i = blockIdx.x*256 + threadIdx.x;
  if (i >= n*16) return;
  int r = i>>4, c = (i&15)*8;
  int vr = vals[r];
  float vb[8];
  if (wf32){
    float4 f0 = *(const float4*)((const float*)emb + (size_t)vr*DD + c);
    float4 f1 = *(const float4*)((const float*)emb + (size_t)vr*DD + c + 4);
    vb[0]=f0.x; vb[1]=f0.y; vb[2]=f0.z; vb[3]=f0.w;
    vb[4]=f1.x; vb[5]=f1.y; vb[6]=f1.z; vb[7]=f1.w;
  } else {
    uint4 raw = *(const uint4*)((const unsigned short*)emb + (size_t)vr*DD + c);
    const unsigned short* hw = (const unsigned short*)&raw;
#pragma unroll
    for (int j=0;j<8;j++) vb[j] = b2f(hw[j]);
  }
  if (OUTB){
    unsigned short* d = (unsigned short*)dstv + (size_t)r*DD + c;
    us4 o0, o1;
    o0.x=f2b(vb[0]); o0.y=f2b(vb[1]); o0.z=f2b(vb[2]); o0.w=f2b(vb[3]);
    o1.x=f2b(vb[4]); o1.y=f2b(vb[5]); o1.z=f2b(vb[6]); o1.w=f2b(vb[7]);
    *(us4*)d = o0; *(us4*)(d+4) = o1;
  } else {
    float* d = (float*)dstv + (size_t)r*DD + c;
    *(float4*)d     = make_float4(vb[0],vb[1],vb[2],vb[3]);
    *(float4*)(d+4) = make_float4(vb[4],vb[5],vb[6],vb[7]);
  }
}

__global__ __launch_bounds__(256) void zerof(float* __restrict__ p, long n4){
  long i = (long)blockIdx.x*256 + threadIdx.x;
  if (i < n4) ((float4*)p)[i] = make_float4(0.f,0.f,0.f,0.f);
}
__global__ __launch_bounds__(256) void zeroi(int* __restrict__ p, int n){
  int i = blockIdx.x*256 + threadIdx.x;
  if (i < n) p[i] = 0;
}

// ---------------- CSR build (by dst) ----------------
__global__ __launch_bounds__(256) void k_hist(const int* __restrict__ dst,
                                              int* __restrict__ deg, int E){
  int i = blockIdx.x*256 + threadIdx.x;
  if (i < E) atomicAdd(&deg[dst[i]], 1);
}

__global__ __launch_bounds__(256) void k_scan1(const int* __restrict__ deg,
                                               int* __restrict__ rowptr,
                                               int* __restrict__ bsum, int n){
  __shared__ int ls[256];
  int b = blockIdx.x, t = threadIdx.x;
  int base = b*1024 + t*4;
  int v0 = (base+0<n)?deg[base+0]:0;
  int v1 = (base+1<n)?deg[base+1]:0;
  int v2 = (base+2<n)?deg[base+2]:0;
  int v3 = (base+3<n)?deg[base+3]:0;
  int tsum = v0+v1+v2+v3;
  ls[t] = tsum; __syncthreads();
  for (int o=1;o<256;o<<=1){
    int x = (t>=o) ? ls[t-o] : 0;
    __syncthreads();
    ls[t] += x;
    __syncthreads();
  }
  int excl = ls[t]-tsum;
  if (t==255) bsum[b] = ls[255];
  if (base+0<n) rowptr[base+0]=excl;
  if (base+1<n) rowptr[base+1]=excl+v0;
  if (base+2<n) rowptr[base+2]=excl+v0+v1;
  if (base+3<n) rowptr[base+3]=excl+v0+v1+v2;
}

__global__ __launch_bounds__(64) void k_scan2(int* __restrict__ bsum, int nb,
                                              int* __restrict__ rowptr, int n){
  if (threadIdx.x==0){
    int run = 0;
    for (int b=0;b<nb;b++){ int x = bsum[b]; bsum[b] = run; run += x; }
    rowptr[n] = run;
  }
}

__global__ __launch_bounds__(256) void k_scan3(int* __restrict__ rowptr,
                                               const int* __restrict__ bsum,
                                               int* __restrict__ cursor, int n){
  int i = blockIdx.x*256 + threadIdx.x;
  if (i < n){
    int r = rowptr[i] + bsum[i>>10];
    rowptr[i] = r;
    cursor[i] = r;
  }
}

__global__ __launch_bounds__(256) void k_scatter(const int* __restrict__ dst,
                                                 int* __restrict__ cursor,
                                                 int* __restrict__ eidx, int E){
  int e = blockIdx.x*256 + threadIdx.x;
  if (e < E){
    int p = atomicAdd(&cursor[dst[e]], 1);
    eidx[p] = e;
  }
}

// ---------------- meta-graph edges (tiny, atomic version) ----------------
__global__ __launch_bounds__(256) void edge_meta(
    const int* __restrict__ src, const int* __restrict__ dst,
    const unsigned short* __restrict__ qm, const unsigned short* __restrict__ kfm,
    const unsigned short* __restrict__ vm,
    const float* __restrict__ base, unsigned short* __restrict__ mef,
    float* __restrict__ z, float* __restrict__ agg, int E)
{
  int e = blockIdx.x*4 + (threadIdx.x>>6);
  if (e >= E) return;
  int lane = threadIdx.x & 63;
  int s = src[e], d = dst[e];
  const float* be2 = base+152; const float* be1 = base+16; const float* bn1 = base+8;
  size_t so=(size_t)s*DD, dq=(size_t)d*DD, eo=(size_t)e*DD;
  float ke0 = b2f(kfm[so+lane])    * be2[lane];
  float ke1 = b2f(kfm[so+64+lane]) * be2[64+lane];
  mef[eo+lane]=f2b(ke0); mef[eo+64+lane]=f2b(ke1);
  float p0 = b2f(qm[dq+lane])*ke0, p1 = b2f(qm[dq+64+lane])*ke1;
#pragma unroll
  for (int m=1;m<16;m<<=1){ p0 += __shfl_xor(p0,m,64); p1 += __shfl_xor(p1,m,64); }
  int h0 = lane>>4, h1 = h0+4;
  float s0 = p0*0.25f + be1[h0] + bn1[h0];
  float s1 = p1*0.25f + be1[h1] + bn1[h1];
  float e0 = __expf(s0), e1 = __expf(s1);
  if ((lane&15)==0){ atomicAdd(&z[(size_t)d*HH+h0], e0); atomicAdd(&z[(size_t)d*HH+h1], e1); }
  atomicAdd(&agg[dq+lane],    e0*b2f(vm[so+lane]));
  atomicAdd(&agg[dq+64+lane], e1*b2f(vm[so+64+lane]));
}

// ---------------- big-graph: fused scores+agg, 4 edges/wave in parallel --------
// lane = grp*16 + l16. Group grp handles edges i0+grp, i0+grp+4, ...
// Lane covers 8 contiguous dims c8=l16*8 (one head: h=l16>>1); 16B loads.
__global__ __launch_bounds__(256) void edge_fused(
    const int* __restrict__ rowptr, const int* __restrict__ eidx,
    const int* __restrict__ src, const int* __restrict__ meid,
    const int* __restrict__ mnid,
    const unsigned short* __restrict__ q, const unsigned short* __restrict__ kf,
    const unsigned short* __restrict__ v,
    const unsigned short* __restrict__ p2me, const unsigned short* __restrict__ p1me,
    const float* __restrict__ p1mn, const float* __restrict__ base,
    float* __restrict__ z, float* __restrict__ agg, int N)
{
  int d = blockIdx.x*4 + (threadIdx.x>>6);
  if (d >= N) return;
  int lane = threadIdx.x & 63;
  int grp = lane >> 4, l16 = lane & 15;
  int c8 = l16 * 8;
  int h = l16 >> 1;
  size_t dq = (size_t)d*DD;
  const float* be2 = base+152; const float* be1 = base+16; const float* bn1 = base+8;

  // per-dst constants
  float qv[8], w2[8];
  {
    uint4 qraw = *(const uint4*)(q + dq + c8);
    const unsigned short* qh = (const unsigned short*)&qraw;
#pragma unroll
    for (int j=0;j<8;j++){ qv[j] = b2f(qh[j]); w2[j] = be2[c8+j]; }
  }
  int mn = mnid[d];
  float bias = be1[h] + bn1[h] + p1mn[(size_t)mn*HH + h];

  float zh = 0.f;
  float a[8];
#pragma unroll
  for (int j=0;j<8;j++) a[j] = 0.f;

  int i0 = rowptr[d], i1 = rowptr[d+1];
  for (int i = i0 + grp; i < i1; i += 4){
    int e = eidx[i];
    int s = src[e], me = meid[e];
    size_t so = (size_t)s*DD, mo = (size_t)me*DD;
    uint4 kraw = *(const uint4*)(kf + so + c8);
    uint4 praw = *(const uint4*)(p2me + mo + c8);
    uint4 vraw = *(const uint4*)(v + so + c8);
    float pm = b2f(p1me[(size_t)me*HH + h]);
    const unsigned short* kh = (const unsigned short*)&kraw;
    const unsigned short* ph = (const unsigned short*)&praw;
    const unsigned short* vh = (const unsigned short*)&vraw;
    float p = 0.f;
#pragma unroll
    for (int j=0;j<8;j++) p += qv[j]*(b2f(kh[j])*(w2[j] + b2f(ph[j])));
    p += __shfl_xor(p, 1, 64);                 // combine the head's two lanes
    float ex = __expf(p*0.25f + bias + pm);
    zh += ex;
#pragma unroll
    for (int j=0;j<8;j++) a[j] += ex*b2f(vh[j]);
  }

  // cross-group combine (xor bits 4,5)
  zh += __shfl_xor(zh, 16, 64); zh += __shfl_xor(zh, 32, 64);
#pragma unroll
  for (int j=0;j<8;j++){
    a[j] += __shfl_xor(a[j], 16, 64);
    a[j] += __shfl_xor(a[j], 32, 64);
  }
  if (grp == 0){
    *(float4*)(agg + dq + c8)     = make_float4(a[0],a[1],a[2],a[3]);
    *(float4*)(agg + dq + c8 + 4) = make_float4(a[4],a[5],a[6],a[7]);
    if ((l16 & 1) == 0) z[(size_t)d*HH + h] = zh;
  }
}

template<bool XB, bool PB>
__global__ __launch_bounds__(128) void learner(
    const void* __restrict__ X, const void* __restrict__ u,
    const void* __restrict__ W2, const void* __restrict__ W1,
    void* __restrict__ p2, void* __restrict__ p1, const int* __restrict__ dflag)
{
  __shared__ float sX[128];
  __shared__ float st[16];
  __shared__ float sw[16];
  const bool wf32 = (*dflag) != 0;
  const int m = blockIdx.x, t = threadIdx.x;
  if (XB) sX[t] = b2f(((const unsigned short*)X)[(size_t)m*DD + t]);
  else    sX[t] = ((const float*)X)[(size_t)m*DD + t];
  __syncthreads();
  int l = t>>3, j = t&7;
  float part = 0.f;
  for (int d=j*16; d<j*16+16; d++) part += sX[d]*gld(u, l*128+d, wf32);
  part += __shfl_xor(part,1,64); part += __shfl_xor(part,2,64); part += __shfl_xor(part,4,64);
  if (j==0) st[l] = part * 0.08838834764831845f;
  __syncthreads();
  float mx=-1e30f;
  for (int i=0;i<16;i++) mx = fmaxf(mx, st[i]);
  float ssum=0.f;
  for (int i=0;i<16;i++) ssum += __expf(st[i]-mx);
  float inv = 1.f/ssum;
  if (t<16) sw[t] = __expf(st[t]-mx)*inv;
  __syncthreads();
  float a=0.f;
  for (int i=0;i<16;i++) a += sw[i]*gld(W2, i*128+t, wf32);
  if (PB) ((unsigned short*)p2)[(size_t)m*DD+t] = f2b(a);
  else    ((float*)p2)[(size_t)m*DD+t] = a;
  if (t<8){
    float bb=0.f;
    for (int i=0;i<16;i++) bb += sw[i]*gld(W1, i*8+t, wf32);
    if (PB) ((unsigned short*)p1)[(size_t)m*HH+t] = f2b(bb);
    else    ((float*)p1)[(size_t)m*HH+t] = bb;
  }
}

__global__ __launch_bounds__(256) void resadd(float* __restrict__ a, const float* __restrict__ b, int n){
  int i = blockIdx.x*256 + threadIdx.x;
  if (i < n) a[i] += b[i];
}

__global__ __launch_bounds__(256) void readout(
    const int* __restrict__ tgt, const int* __restrict__ mnid,
    const unsigned short* __restrict__ featb, const float* __restrict__ p1mn,
    const float* __restrict__ base, float* __restrict__ acc,
    void* __restrict__ out, int last, float invNB, int BT,
    const int* __restrict__ dflag)
{
  int t = blockIdx.x*256 + threadIdx.x;
  if (t >= BT) return;
  int idx = tgt[t]; int mn = mnid[idx];
  float logit = 0.f;
  for (int h=0;h<8;h++){
    float tw = base[h] + p1mn[(size_t)mn*HH + h];
    float srow = 0.f;
    for (int k=0;k<16;k++) srow += b2f(featb[(size_t)idx*DD + h*16 + k]);
    logit += tw*srow;
  }
  if (!last) acc[t] = logit;
  else {
    float r = (acc[t] + logit) * invNB;
    if ((*dflag) != 0) ((float*)out)[t] = r;
    else ((__hip_bfloat16*)out)[t] = __float2bfloat16(r);
  }
}

extern "C" void kernel_launch(void* const* d_in, const int* in_sizes, int n_in,
                              void* d_out, int out_size, void* d_ws, size_t ws_size,
                              hipStream_t stream) {
  const void* emb   = d_in[0];
  const void* u     = d_in[1];
  const void* W2lat = d_in[2];
  const void* W1lat = d_in[3];
  WPtrs wptrs;
  for (int i=0;i<8;i++) wptrs.p[i] = d_in[4+i];
  const int* node_vals      = (const int*)d_in[12];
  const int* meta_node_vals = (const int*)d_in[13];
  const int* src            = (const int*)d_in[14];
  const int* dst            = (const int*)d_in[15];
  const int* meta_src       = (const int*)d_in[16];
  const int* meta_dst       = (const int*)d_in[17];
  const int* meta_node_id   = (const int*)d_in[18];
  const int* meta_edge_id   = (const int*)d_in[19];
  const int* target_idx     = (const int*)d_in[20];
  const int* static_vals    = (const int*)d_in[21];
  const int* static_src     = (const int*)d_in[22];
  const int* static_dst     = (const int*)d_in[23];

  const int N  = in_sizes[12];
  const int MN = in_sizes[13];
  const int E  = in_sizes[14];
  const int ME = in_sizes[16];
  const int BT = in_sizes[20];
  const int NSRC = in_sizes[22];
  const int NB = in_sizes[8] / (DD*DD);

  float* ws = (float*)d_ws;
  size_t off = 0;
  auto allocf = [&](size_t n){ float* p = ws + off; off += n; return p; };
  auto allocb = [&](size_t n){ unsigned short* p = (unsigned short*)(ws + off); off += (n+1)/2; return p; };
  auto alloci = [&](size_t n){ int* p = (int*)(ws + off); off += n; return p; };
  int*            dflag = (int*)ws; off += 4;
  unsigned short* feat  = allocb((size_t)N*DD);
  unsigned short* q     = allocb((size_t)N*DD);
  unsigned short* kf    = allocb((size_t)N*DD);
  unsigned short* v     = allocb((size_t)N*DD);
  float*          agg   = allocf((size_t)N*DD);
  float*          z     = allocf((size_t)N*HH);
  float*          meta_feat= allocf((size_t)MN*DD);
  float*          agg_m = allocf((size_t)MN*DD);  // z_m contiguous follows
  float*          z_m   = allocf((size_t)MN*HH);
  unsigned short* q_m   = allocb((size_t)MN*DD);
  unsigned short* kf_m  = allocb((size_t)MN*DD);
  unsigned short* v_m   = allocb((size_t)MN*DD);
  float*          meta_out = allocf((size_t)MN*DD);
  unsigned short* mef   = allocb((size_t)ME*DD);
  float*          p2mn  = allocf((size_t)MN*DD);
  float*          p1mn  = allocf((size_t)MN*HH);
  unsigned short* p2me  = allocb((size_t)ME*DD);
  unsigned short* p1me  = allocb((size_t)ME*HH);
  float*          base  = allocf(280);
  float*          acc   = allocf((size_t)BT);
  unsigned short* wstage= allocb((size_t)8*DD*DD);
  int*            rowptr= alloci((size_t)N+1);
  int*            cursor= alloci((size_t)N);
  int*            deg   = alloci((size_t)N);
  int*            eidx  = alloci((size_t)E);
  const int nb_scan = (N + 1023)/1024;
  int*            bsum  = alloci((size_t)nb_scan);
  (void)ws_size; (void)n_in; (void)out_size;

  const float* base_n2 = base + 24;

  k_detect<<<1,64,0,stream>>>((const unsigned short*)emb, dflag);
  k_static<<<1,256,0,stream>>>(emb, static_vals, static_src, static_dst,
                               u, W2lat, W1lat, base, NSRC, dflag);
  gather_rows<true ><<<(N*16+255)/256,256,0,stream>>>(emb, node_vals, feat, N, dflag);
  gather_rows<false><<<(MN*16+255)/256,256,0,stream>>>(emb, meta_node_vals, meta_feat, MN, dflag);

  // ---- CSR build (by dst), once per call ----
  zeroi<<<(N+255)/256,256,0,stream>>>(deg, N);
  k_hist<<<(E+255)/256,256,0,stream>>>(dst, deg, E);
  k_scan1<<<nb_scan,256,0,stream>>>(deg, rowptr, bsum, N);
  k_scan2<<<1,64,0,stream>>>(bsum, nb_scan, rowptr, N);
  k_scan3<<<(N+255)/256,256,0,stream>>>(rowptr, bsum, cursor, N);
  k_scatter<<<(E+255)/256,256,0,stream>>>(dst, cursor, eidx, E);

  const int gm = (MN+63)/64;
  const int gN = (N+63)/64;
  const long nz_meta = ((long)MN*DD + (long)MN*HH)/4;
  const float invNB = 1.0f/(float)NB;

  for (int b=0;b<NB;b++){
    const size_t bo = (size_t)b*DD*DD;
    w_repack8<<<512,256,0,stream>>>(wptrs, wstage, bo, dflag);
    const unsigned short* wq_m = wstage + 0*DD*DD;
    const unsigned short* wk_m = wstage + 1*DD*DD;
    const unsigned short* wv_m = wstage + 2*DD*DD;
    const unsigned short* wo_m = wstage + 3*DD*DD;
    const unsigned short* wqb  = wstage + 4*DD*DD;
    const unsigned short* wkb  = wstage + 5*DD*DD;
    const unsigned short* wvb  = wstage + 6*DD*DD;
    const unsigned short* wob  = wstage + 7*DD*DD;

    // ---- meta conv (broadcast base params) ----
    gemm_qkv<EPI_SCALE_CONST,false><<<gm,256,0,stream>>>(meta_feat, wq_m, wk_m, wv_m,
        q_m, kf_m, v_m, MN, base_n2, nullptr, nullptr);
    zerof<<<(int)((nz_meta+255)/256),256,0,stream>>>(agg_m, nz_meta);
    edge_meta<<<(ME+3)/4,256,0,stream>>>(meta_src, meta_dst, q_m, kf_m, v_m,
        base, mef, z_m, agg_m, ME);
    gemm128m<EPI_RELU,true,false,false><<<gm,256,0,stream>>>(agg_m, wo_m, meta_out, MN,
        z_m, nullptr, nullptr, nullptr, nullptr);

    // ---- meta learners (pre-residual conv outputs) ----
    learner<false,false><<<MN,128,0,stream>>>(meta_out, u, W2lat, W1lat, p2mn, p1mn, dflag);
    learner<true ,true ><<<ME,128,0,stream>>>(mef,      u, W2lat, W1lat, p2me, p1me, dflag);
    resadd<<<(MN*DD+255)/256,256,0,stream>>>(meta_feat, meta_out, MN*DD);

    // ---- big conv ----
    gemm_qkv<EPI_SCALE_GATHER,true><<<gN,256,0,stream>>>(feat, wqb, wkb, wvb,
        q, kf, v, N, base_n2, p2mn, meta_node_id);
    edge_fused<<<(N+3)/4,256,0,stream>>>(rowptr, eidx, src, meta_edge_id,
        meta_node_id, q, kf, v, p2me, p1me, p1mn, base, z, agg, N);
    gemm128m<EPI_RELU_RES,true,false,true><<<gN,256,0,stream>>>(agg, wob, feat, N,
        z, nullptr, nullptr, nullptr, feat);

    // ---- readout ----
    readout<<<(BT+255)/256,256,0,stream>>>(target_idx, meta_node_id, feat, p1mn,
        base, acc, d_out, (b==NB-1) ? 1 : 0, invNB, BT, dflag);
  }
}

// Round 9
// 798.853 us; speedup vs baseline: 1.1146x; 1.1146x over previous
//
#include <hip/hip_runtime.h>
#include <hip/hip_bf16.h>

#define DD   128
#define HH   8

typedef short bf16x8 __attribute__((ext_vector_type(8)));
typedef float f32x4  __attribute__((ext_vector_type(4)));

__device__ __forceinline__ float b2f(unsigned short v){
  union { unsigned int u; float f; } x; x.u = ((unsigned int)v) << 16; return x.f;
}
__device__ __forceinline__ unsigned short f2b(float f){
  __hip_bfloat16 h = __float2bfloat16(f);
  return *(unsigned short*)&h;
}
struct __align__(8) us4 { unsigned short x,y,z,w; };

__device__ __forceinline__ float gld(const void* p, size_t i, bool f32){
  if (f32) return ((const float*)p)[i];
  return b2f(((const unsigned short*)p)[i]);
}

// Detect input float dtype. emb ~ N(0,1)*0.05. If f32, odd ushorts are mantissa
// garbage -> huge "bf16" values. flag=1 -> inputs are f32.
__global__ __launch_bounds__(64) void k_detect(const unsigned short* __restrict__ emb,
                                               int* __restrict__ flag){
  int t = threadIdx.x;
  float m = 0.f;
  for (int i=t; i<128; i+=64){
    float x = fabsf(b2f(emb[i]));
    if (x < 1e30f) m = fmaxf(m, x);
  }
#pragma unroll
  for (int s=1;s<64;s<<=1) m = fmaxf(m, __shfl_xor(m, s, 64));
  if (t==0) *flag = (m > 1e4f) ? 1 : 0;
}

// All 8 weight blocks -> bf16 TRANSPOSED staging ([n][k]) in one launch.
struct WPtrs { const void* p[8]; };
__global__ __launch_bounds__(256) void w_repack8(
    WPtrs W, unsigned short* __restrict__ stage,
    size_t bo, const int* __restrict__ dflag)
{
  const bool wf32 = (*dflag) != 0;
  int mat = blockIdx.x >> 6;
  int i = (blockIdx.x & 63)*256 + threadIdx.x;
  int k = i >> 7, n = i & 127;
  float x;
  if (wf32) x = ((const float*)W.p[mat])[bo + i];
  else      x = b2f(((const unsigned short*)W.p[mat])[bo + i]);
  stage[(size_t)mat*DD*DD + n*DD + k] = f2b(x);
}

enum { EPI_STORE=0, EPI_SCALE_CONST=1, EPI_SCALE_GATHER=2, EPI_RELU=3, EPI_RELU_RES=4 };

#define APAD 136   // 128 + 8 bf16: breaks stride-256B bank aliasing
#define CPAD 132   // f32 row pad for epilogue repack

// C[M,128] = epi( prologue(A)[M,128] @ B[128,128] ), B bf16 TRANSPOSED ([n][k]).
template<int EPI, bool NORM, bool INB, bool OUTB>
__global__ __launch_bounds__(256) void gemm128m(
    const void* __restrict__ Av, const unsigned short* __restrict__ Bt,
    void* __restrict__ Cv, int M,
    const float* __restrict__ z, const float* __restrict__ svec,
    const float* __restrict__ P2, const int* __restrict__ gidx,
    const unsigned short* __restrict__ Rb)
{
  __shared__ unsigned short Asb[64*APAD];    // [row][k] bf16
  __shared__ unsigned short Btb[128*APAD];   // [n][k] bf16; aliased by C f32 later
  const int tid = threadIdx.x;
  const int wave = tid >> 6, lane = tid & 63;
  const int row0 = blockIdx.x * 64;

  {
    int r = tid >> 2, cb = (tid & 3) * 32;
    int gr = row0 + r;
    if (INB){
      const unsigned short* Ab = (const unsigned short*)Av;
#pragma unroll
      for (int j=0;j<4;j++){
        int c = cb + j*8;
        uint4 raw = make_uint4(0,0,0,0);
        if (gr < M) raw = *(const uint4*)(Ab + (size_t)gr*DD + c);
        *(uint4*)&Asb[r*APAD + c] = raw;
      }
    } else {
      const float* Af = (const float*)Av;
#pragma unroll
      for (int j=0;j<8;j++){
        int c = cb + j*4;
        float4 val = make_float4(0.f,0.f,0.f,0.f);
        if (gr < M){
          val = *(const float4*)(Af + (size_t)gr*DD + c);
          if (NORM){
            float s = 1.0f / (z[(size_t)gr*HH + (c>>4)] + 1e-9f);
            val.x*=s; val.y*=s; val.z*=s; val.w*=s;
          }
        }
        us4 o; o.x=f2b(val.x); o.y=f2b(val.y); o.z=f2b(val.z); o.w=f2b(val.w);
        *(us4*)&Asb[r*APAD + c] = o;
      }
    }
  }
  {
    int n = tid >> 1, k0s = (tid & 1) * 64;
#pragma unroll
    for (int j=0;j<8;j++){
      uint4 raw = *(const uint4*)(Bt + (size_t)n*DD + k0s + j*8);
      *(uint4*)&Btb[n*APAD + k0s + j*8] = raw;
    }
  }
  __syncthreads();

  f32x4 acc[8];
#pragma unroll
  for (int t=0;t<8;t++) acc[t] = (f32x4){0.f,0.f,0.f,0.f};
  const int am = (lane & 15), kq = (lane >> 4) * 8;
#pragma unroll
  for (int k0=0;k0<128;k0+=32){
    bf16x8 a = *(bf16x8*)&Asb[(wave*16 + am)*APAD + k0 + kq];
#pragma unroll
    for (int t=0;t<8;t++){
      bf16x8 b = *(bf16x8*)&Btb[(t*16 + am)*APAD + k0 + kq];
      acc[t] = __builtin_amdgcn_mfma_f32_16x16x32_bf16(a, b, acc[t], 0,0,0);
    }
  }
  __syncthreads();
  float* Cls = (float*)Btb;   // [64][CPAD] f32
  {
    int rr = wave*16 + (lane>>4)*4;
    int cc = lane & 15;
#pragma unroll
    for (int t=0;t<8;t++)
#pragma unroll
      for (int r=0;r<4;r++)
        Cls[(rr + r)*CPAD + t*16 + cc] = acc[t][r];
  }
  __syncthreads();

  {
    int r = tid >> 2, cb = (tid & 3) * 32;
    int gr = row0 + r;
    if (gr < M){
#pragma unroll
      for (int j=0;j<8;j++){
        int c = cb + j*4;
        float4 o = *(float4*)&Cls[r*CPAD + c];
        if (EPI == EPI_SCALE_CONST){
          o.x*=svec[c+0]; o.y*=svec[c+1]; o.z*=svec[c+2]; o.w*=svec[c+3];
        } else if (EPI == EPI_SCALE_GATHER){
          int g = gidx[gr];
          const float* p = P2 + (size_t)g*DD + c;
          o.x*=(svec[c+0]+p[0]); o.y*=(svec[c+1]+p[1]);
          o.z*=(svec[c+2]+p[2]); o.w*=(svec[c+3]+p[3]);
        } else if (EPI == EPI_RELU){
          o.x=fmaxf(o.x,0.f); o.y=fmaxf(o.y,0.f); o.z=fmaxf(o.z,0.f); o.w=fmaxf(o.w,0.f);
        } else if (EPI == EPI_RELU_RES){
          us4 rb = *(const us4*)(Rb + (size_t)gr*DD + c);
          o.x=fmaxf(o.x,0.f)+b2f(rb.x); o.y=fmaxf(o.y,0.f)+b2f(rb.y);
          o.z=fmaxf(o.z,0.f)+b2f(rb.z); o.w=fmaxf(o.w,0.f)+b2f(rb.w);
        }
        if (OUTB){
          us4 ob; ob.x=f2b(o.x); ob.y=f2b(o.y); ob.z=f2b(o.z); ob.w=f2b(o.w);
          *(us4*)((unsigned short*)Cv + (size_t)gr*DD + c) = ob;
        } else {
          *(float4*)((float*)Cv + (size_t)gr*DD + c) = o;
        }
      }
    }
  }
}

// Fused Q/K/V gemm: stage A once, run 3 weight matrices through the same LDS.
// Per-phase output stride (stK/stV) lets K,V interleave into one kv buffer.
template<int EPIQ, bool INB>
__global__ __launch_bounds__(256) void gemm_qkv(
    const void* __restrict__ Av,
    const unsigned short* __restrict__ Btq, const unsigned short* __restrict__ Btk,
    const unsigned short* __restrict__ Btv,
    unsigned short* __restrict__ Cq, unsigned short* __restrict__ Ck, int stK,
    unsigned short* __restrict__ Cvo, int stV, int M,
    const float* __restrict__ svec, const float* __restrict__ P2,
    const int* __restrict__ gidx)
{
  __shared__ unsigned short Asb[64*APAD];
  __shared__ unsigned short Btb[128*APAD];
  const int tid = threadIdx.x;
  const int wave = tid >> 6, lane = tid & 63;
  const int row0 = blockIdx.x * 64;

  {
    int r = tid >> 2, cb = (tid & 3) * 32;
    int gr = row0 + r;
    if (INB){
      const unsigned short* Ab = (const unsigned short*)Av;
#pragma unroll
      for (int j=0;j<4;j++){
        int c = cb + j*8;
        uint4 raw = make_uint4(0,0,0,0);
        if (gr < M) raw = *(const uint4*)(Ab + (size_t)gr*DD + c);
        *(uint4*)&Asb[r*APAD + c] = raw;
      }
    } else {
      const float* Af = (const float*)Av;
#pragma unroll
      for (int j=0;j<8;j++){
        int c = cb + j*4;
        float4 val = make_float4(0.f,0.f,0.f,0.f);
        if (gr < M) val = *(const float4*)(Af + (size_t)gr*DD + c);
        us4 o; o.x=f2b(val.x); o.y=f2b(val.y); o.z=f2b(val.z); o.w=f2b(val.w);
        *(us4*)&Asb[r*APAD + c] = o;
      }
    }
  }

  const unsigned short* Bts[3] = {Btq, Btk, Btv};
  unsigned short* Cs[3] = {Cq, Ck, Cvo};
  const int sts[3] = {DD, stK, stV};
  const int am = (lane & 15), kq = (lane >> 4) * 8;

  for (int ph=0; ph<3; ph++){
    {
      int n = tid >> 1, k0s = (tid & 1) * 64;
      const unsigned short* Bt = Bts[ph];
#pragma unroll
      for (int j=0;j<8;j++){
        uint4 raw = *(const uint4*)(Bt + (size_t)n*DD + k0s + j*8);
        *(uint4*)&Btb[n*APAD + k0s + j*8] = raw;
      }
    }
    __syncthreads();
    f32x4 acc[8];
#pragma unroll
    for (int t=0;t<8;t++) acc[t] = (f32x4){0.f,0.f,0.f,0.f};
#pragma unroll
    for (int k0=0;k0<128;k0+=32){
      bf16x8 a = *(bf16x8*)&Asb[(wave*16 + am)*APAD + k0 + kq];
#pragma unroll
      for (int t=0;t<8;t++){
        bf16x8 b = *(bf16x8*)&Btb[(t*16 + am)*APAD + k0 + kq];
        acc[t] = __builtin_amdgcn_mfma_f32_16x16x32_bf16(a, b, acc[t], 0,0,0);
      }
    }
    __syncthreads();
    float* Cls = (float*)Btb;
    {
      int rr = wave*16 + (lane>>4)*4;
      int cc = lane & 15;
#pragma unroll
      for (int t=0;t<8;t++)
#pragma unroll
        for (int r=0;r<4;r++)
          Cls[(rr + r)*CPAD + t*16 + cc] = acc[t][r];
    }
    __syncthreads();
    {
      int r = tid >> 2, cb = (tid & 3) * 32;
      int gr = row0 + r;
      if (gr < M){
#pragma unroll
        for (int j=0;j<8;j++){
          int c = cb + j*4;
          float4 o = *(float4*)&Cls[r*CPAD + c];
          if (ph == 0){
            if (EPIQ == EPI_SCALE_GATHER){
              int g = gidx[gr];
              const float* p = P2 + (size_t)g*DD + c;
              o.x*=(svec[c+0]+p[0]); o.y*=(svec[c+1]+p[1]);
              o.z*=(svec[c+2]+p[2]); o.w*=(svec[c+3]+p[3]);
            } else { // SCALE_CONST
              o.x*=svec[c+0]; o.y*=svec[c+1]; o.z*=svec[c+2]; o.w*=svec[c+3];
            }
          }
          us4 ob; ob.x=f2b(o.x); ob.y=f2b(o.y); ob.z=f2b(o.z); ob.w=f2b(o.w);
          *(us4*)(Cs[ph] + (size_t)gr*sts[ph] + c) = ob;
        }
      }
    }
    __syncthreads();
  }
}

// Static param-name graph -> base params. base: [0..7]=tw,[8..15]=n1,[16..23]=e1,
// [24..151]=n2,[152..279]=e2
__global__ __launch_bounds__(256) void k_static(
    const void* __restrict__ emb, const int* __restrict__ svals,
    const int* __restrict__ ssrc, const int* __restrict__ sdst,
    const void* __restrict__ u, const void* __restrict__ W2,
    const void* __restrict__ W1, float* __restrict__ base, int nsrc,
    const int* __restrict__ dflag)
{
  __shared__ float sagg[15][128];
  __shared__ float ssc[15][16];
  __shared__ float sww[15][16];
  const bool wf32 = (*dflag) != 0;
  const int t = threadIdx.x;
  for (int i=t;i<15*128;i+=256) ((float*)sagg)[i]=0.f;
  __syncthreads();
  if (t < 128){
    for (int i=0;i<nsrc;i++){
      int row = sdst[i]; int vr = svals[ssrc[i]];
      sagg[row][t] += gld(emb, (size_t)vr*DD + t, wf32);
    }
  }
  __syncthreads();
  if (t < 240){
    int n = t>>4, l = t&15;
    float a=0.f;
    for (int d=0;d<128;d++) a += sagg[n][d]*gld(u, l*128+d, wf32);
    ssc[n][l] = a * 0.08838834764831845f;
  }
  __syncthreads();
  if (t < 15){
    float mx=-1e30f;
    for (int l=0;l<16;l++) mx = fmaxf(mx, ssc[t][l]);
    float s=0.f;
    for (int l=0;l<16;l++){ float e=__expf(ssc[t][l]-mx); sww[t][l]=e; s+=e; }
    float inv = 1.f/s;
    for (int l=0;l<16;l++) sww[t][l]*=inv;
  }
  __syncthreads();
  if (t < 8){
    float a=0.f,b=0.f,c=0.f;
    for (int l=0;l<16;l++){
      float wv = gld(W1, l*8+t, wf32);
      a += sww[0][l]*wv; b += sww[3][l]*wv; c += sww[9][l]*wv;
    }
    base[t]=a; base[8+t]=b; base[16+t]=c;
  }
  if (t < 128){
    float a=0.f,b=0.f;
    for (int l=0;l<16;l++){
      float wv = gld(W2, l*128+t, wf32);
      a += sww[6][l]*wv; b += sww[12][l]*wv;
    }
    base[24+t]=a; base[152+t]=b;
  }
}

template<bool OUTB>
__global__ __launch_bounds__(256) void gather_rows(
    const void* __restrict__ emb, const int* __restrict__ vals,
    void* __restrict__ dstv, int n, const int* __restrict__ dflag)
{
  const bool wf32 = (*dflag) != 0;
  int i = blockIdx.x*256 + threadIdx.x;
  if (i >= n*16) return;
  int r = i>>4, c = (i&15)*8;
  int vr = vals[r];
  float vb[8];
  if (wf32){
    float4 f0 = *(const float4*)((const float*)emb + (size_t)vr*DD + c);
    float4 f1 = *(const float4*)((const float*)emb + (size_t)vr*DD + c + 4);
    vb[0]=f0.x; vb[1]=f0.y; vb[2]=f0.z; vb[3]=f0.w;
    vb[4]=f1.x; vb[5]=f1.y; vb[6]=f1.z; vb[7]=f1.w;
  } else {
    uint4 raw = *(const uint4*)((const unsigned short*)emb + (size_t)vr*DD + c);
    const unsigned short* hw = (const unsigned short*)&raw;
#pragma unroll
    for (int j=0;j<8;j++) vb[j] = b2f(hw[j]);
  }
  if (OUTB){
    unsigned short* d = (unsigned short*)dstv + (size_t)r*DD + c;
    us4 o0, o1;
    o0.x=f2b(vb[0]); o0.y=f2b(vb[1]); o0.z=f2b(vb[2]); o0.w=f2b(vb[3]);
    o1.x=f2b(vb[4]); o1.y=f2b(vb[5]); o1.z=f2b(vb[6]); o1.w=f2b(vb[7]);
    *(us4*)d = o0; *(us4*)(d+4) = o1;
  } else {
    float* d = (float*)dstv + (size_t)r*DD + c;
    *(float4*)d     = make_float4(vb[0],vb[1],vb[2],vb[3]);
    *(float4*)(d+4) = make_float4(vb[4],vb[5],vb[6],vb[7]);
  }
}

__global__ __launch_bounds__(256) void zerof(float* __restrict__ p, long n4){
  long i = (long)blockIdx.x*256 + threadIdx.x;
  if (i < n4) ((float4*)p)[i] = make_float4(0.f,0.f,0.f,0.f);
}
__global__ __launch_bounds__(256) void zeroi(int* __restrict__ p, int n){
  int i = blockIdx.x*256 + threadIdx.x;
  if (i < n) p[i] = 0;
}

// ---------------- CSR build (by dst) ----------------
__global__ __launch_bounds__(256) void k_hist(const int* __restrict__ dst,
                                              int* __restrict__ deg, int E){
  int i = blockIdx.x*256 + threadIdx.x;
  if (i < E) atomicAdd(&deg[dst[i]], 1);
}

__global__ __launch_bounds__(256) void k_scan1(const int* __restrict__ deg,
                                               int* __restrict__ rowptr,
                                               int* __restrict__ bsum, int n){
  __shared__ int ls[256];
  int b = blockIdx.x, t = threadIdx.x;
  int base = b*1024 + t*4;
  int v0 = (base+0<n)?deg[base+0]:0;
  int v1 = (base+1<n)?deg[base+1]:0;
  int v2 = (base+2<n)?deg[base+2]:0;
  int v3 = (base+3<n)?deg[base+3]:0;
  int tsum = v0+v1+v2+v3;
  ls[t] = tsum; __syncthreads();
  for (int o=1;o<256;o<<=1){
    int x = (t>=o) ? ls[t-o] : 0;
    __syncthreads();
    ls[t] += x;
    __syncthreads();
  }
  int excl = ls[t]-tsum;
  if (t==255) bsum[b] = ls[255];
  if (base+0<n) rowptr[base+0]=excl;
  if (base+1<n) rowptr[base+1]=excl+v0;
  if (base+2<n) rowptr[base+2]=excl+v0+v1;
  if (base+3<n) rowptr[base+3]=excl+v0+v1+v2;
}

__global__ __launch_bounds__(64) void k_scan2(int* __restrict__ bsum, int nb,
                                              int* __restrict__ rowptr, int n){
  if (threadIdx.x==0){
    int run = 0;
    for (int b=0;b<nb;b++){ int x = bsum[b]; bsum[b] = run; run += x; }
    rowptr[n] = run;
  }
}

__global__ __launch_bounds__(256) void k_scan3(int* __restrict__ rowptr,
                                               const int* __restrict__ bsum,
                                               int* __restrict__ cursor, int n){
  int i = blockIdx.x*256 + threadIdx.x;
  if (i < n){
    int r = rowptr[i] + bsum[i>>10];
    rowptr[i] = r;
    cursor[i] = r;
  }
}

// scatter src/meid directly into CSR order (removes eidx indirection at use site)
__global__ __launch_bounds__(256) void k_scatter(const int* __restrict__ dst,
                                                 const int* __restrict__ src,
                                                 const int* __restrict__ meid,
                                                 int* __restrict__ cursor,
                                                 int* __restrict__ esrc,
                                                 int* __restrict__ emeid, int E){
  int e = blockIdx.x*256 + threadIdx.x;
  if (e < E){
    int p = atomicAdd(&cursor[dst[e]], 1);
    esrc[p]  = src[e];
    emeid[p] = meid[e];
  }
}

// ---------------- meta-graph edges (tiny, atomic version) ----------------
__global__ __launch_bounds__(256) void edge_meta(
    const int* __restrict__ src, const int* __restrict__ dst,
    const unsigned short* __restrict__ qm, const unsigned short* __restrict__ kfm,
    const unsigned short* __restrict__ vm,
    const float* __restrict__ base, unsigned short* __restrict__ mef,
    float* __restrict__ z, float* __restrict__ agg, int E)
{
  int e = blockIdx.x*4 + (threadIdx.x>>6);
  if (e >= E) return;
  int lane = threadIdx.x & 63;
  int s = src[e], d = dst[e];
  const float* be2 = base+152; const float* be1 = base+16; const float* bn1 = base+8;
  size_t so=(size_t)s*DD, dq=(size_t)d*DD, eo=(size_t)e*DD;
  float ke0 = b2f(kfm[so+lane])    * be2[lane];
  float ke1 = b2f(kfm[so+64+lane]) * be2[64+lane];
  mef[eo+lane]=f2b(ke0); mef[eo+64+lane]=f2b(ke1);
  float p0 = b2f(qm[dq+lane])*ke0, p1 = b2f(qm[dq+64+lane])*ke1;
#pragma unroll
  for (int m=1;m<16;m<<=1){ p0 += __shfl_xor(p0,m,64); p1 += __shfl_xor(p1,m,64); }
  int h0 = lane>>4, h1 = h0+4;
  float s0 = p0*0.25f + be1[h0] + bn1[h0];
  float s1 = p1*0.25f + be1[h1] + bn1[h1];
  float e0 = __expf(s0), e1 = __expf(s1);
  if ((lane&15)==0){ atomicAdd(&z[(size_t)d*HH+h0], e0); atomicAdd(&z[(size_t)d*HH+h1], e1); }
  atomicAdd(&agg[dq+lane],    e0*b2f(vm[so+lane]));
  atomicAdd(&agg[dq+64+lane], e1*b2f(vm[so+64+lane]));
}

// ---------------- big-graph: fused scores+agg, 4 edges/wave, streamed indices ---
// kv layout: [node][256] = kf row (128) ++ v row (128) -> one 512B random region/edge.
// lane = grp*16 + l16; group grp owns edges i0+grp, i0+grp+4, ... ; unroll-2.
__global__ __launch_bounds__(256) void edge_fused(
    const int* __restrict__ rowptr,
    const int* __restrict__ esrc, const int* __restrict__ emeid,
    const int* __restrict__ mnid,
    const unsigned short* __restrict__ q, const unsigned short* __restrict__ kv,
    const unsigned short* __restrict__ p2me, const unsigned short* __restrict__ p1me,
    const float* __restrict__ p1mn, const float* __restrict__ base,
    float* __restrict__ z, float* __restrict__ agg, int N)
{
  int d = blockIdx.x*4 + (threadIdx.x>>6);
  if (d >= N) return;
  int lane = threadIdx.x & 63;
  int grp = lane >> 4, l16 = lane & 15;
  int c8 = l16 * 8;
  int h = l16 >> 1;
  size_t dq = (size_t)d*DD;
  const float* be2 = base+152; const float* be1 = base+16; const float* bn1 = base+8;

  float qv[8], w2[8];
  {
    uint4 qraw = *(const uint4*)(q + dq + c8);
    const unsigned short* qh = (const unsigned short*)&qraw;
#pragma unroll
    for (int j=0;j<8;j++){ qv[j] = b2f(qh[j]); w2[j] = be2[c8+j]; }
  }
  int mn = mnid[d];
  float bias = be1[h] + bn1[h] + p1mn[(size_t)mn*HH + h];

  float zh = 0.f;
  float a[8];
#pragma unroll
  for (int j=0;j<8;j++) a[j] = 0.f;

  int i0 = rowptr[d], i1 = rowptr[d+1];
  int i = i0 + grp;
  // unroll-2: edges i and i+4 in flight together
  for (; i + 4 < i1; i += 8){
    int s0 = esrc[i],   me0 = emeid[i];
    int s1 = esrc[i+4], me1 = emeid[i+4];
    size_t kvo0 = (size_t)s0*(2*DD), mo0 = (size_t)me0*DD;
    size_t kvo1 = (size_t)s1*(2*DD), mo1 = (size_t)me1*DD;
    uint4 kraw0 = *(const uint4*)(kv + kvo0 + c8);
    uint4 vraw0 = *(const uint4*)(kv + kvo0 + DD + c8);
    uint4 praw0 = *(const uint4*)(p2me + mo0 + c8);
    float pm0 = b2f(p1me[(size_t)me0*HH + h]);
    uint4 kraw1 = *(const uint4*)(kv + kvo1 + c8);
    uint4 vraw1 = *(const uint4*)(kv + kvo1 + DD + c8);
    uint4 praw1 = *(const uint4*)(p2me + mo1 + c8);
    float pm1 = b2f(p1me[(size_t)me1*HH + h]);
    const unsigned short* kh0 = (const unsigned short*)&kraw0;
    const unsigned short* ph0 = (const unsigned short*)&praw0;
    const unsigned short* vh0 = (const unsigned short*)&vraw0;
    const unsigned short* kh1 = (const unsigned short*)&kraw1;
    const unsigned short* ph1 = (const unsigned short*)&praw1;
    const unsigned short* vh1 = (const unsigned short*)&vraw1;
    float pA = 0.f, pB = 0.f;
#pragma unroll
    for (int j=0;j<8;j++){
      pA += qv[j]*(b2f(kh0[j])*(w2[j] + b2f(ph0[j])));
      pB += qv[j]*(b2f(kh1[j])*(w2[j] + b2f(ph1[j])));
    }
    pA += __shfl_xor(pA, 1, 64);
    pB += __shfl_xor(pB, 1, 64);
    float ex0 = __expf(pA*0.25f + bias + pm0);
    float ex1 = __expf(pB*0.25f + bias + pm1);
    zh += ex0 + ex1;
#pragma unroll
    for (int j=0;j<8;j++) a[j] += ex0*b2f(vh0[j]) + ex1*b2f(vh1[j]);
  }
  if (i < i1){
    int s = esrc[i], me = emeid[i];
    size_t kvo = (size_t)s*(2*DD), mo = (size_t)me*DD;
    uint4 kraw = *(const uint4*)(kv + kvo + c8);
    uint4 vraw = *(const uint4*)(kv + kvo + DD + c8);
    uint4 praw = *(const uint4*)(p2me + mo + c8);
    float pm = b2f(p1me[(size_t)me*HH + h]);
    const unsigned short* kh = (const unsigned short*)&kraw;
    const unsigned short* ph = (const unsigned short*)&praw;
    const unsigned short* vh = (const unsigned short*)&vraw;
    float p = 0.f;
#pragma unroll
    for (int j=0;j<8;j++) p += qv[j]*(b2f(kh[j])*(w2[j] + b2f(ph[j])));
    p += __shfl_xor(p, 1, 64);
    float ex = __expf(p*0.25f + bias + pm);
    zh += ex;
#pragma unroll
    for (int j=0;j<8;j++) a[j] += ex*b2f(vh[j]);
  }

  // cross-group combine (xor bits 4,5)
  zh += __shfl_xor(zh, 16, 64); zh += __shfl_xor(zh, 32, 64);
#pragma unroll
  for (int j=0;j<8;j++){
    a[j] += __shfl_xor(a[j], 16, 64);
    a[j] += __shfl_xor(a[j], 32, 64);
  }
  if (grp == 0){
    *(float4*)(agg + dq + c8)     = make_float4(a[0],a[1],a[2],a[3]);
    *(float4*)(agg + dq + c8 + 4) = make_float4(a[4],a[5],a[6],a[7]);
    if ((l16 & 1) == 0) z[(size_t)d*HH + h] = zh;
  }
}

template<bool XB, bool PB>
__global__ __launch_bounds__(128) void learner(
    const void* __restrict__ X, const void* __restrict__ u,
    const void* __restrict__ W2, const void* __restrict__ W1,
    void* __restrict__ p2, void* __restrict__ p1, const int* __restrict__ dflag)
{
  __shared__ float sX[128];
  __shared__ float st[16];
  __shared__ float sw[16];
  const bool wf32 = (*dflag) != 0;
  const int m = blockIdx.x, t = threadIdx.x;
  if (XB) sX[t] = b2f(((const unsigned short*)X)[(size_t)m*DD + t]);
  else    sX[t] = ((const float*)X)[(size_t)m*DD + t];
  __syncthreads();
  int l = t>>3, j = t&7;
  float part = 0.f;
  for (int d=j*16; d<j*16+16; d++) part += sX[d]*gld(u, l*128+d, wf32);
  part += __shfl_xor(part,1,64); part += __shfl_xor(part,2,64); part += __shfl_xor(part,4,64);
  if (j==0) st[l] = part * 0.08838834764831845f;
  __syncthreads();
  float mx=-1e30f;
  for (int i=0;i<16;i++) mx = fmaxf(mx, st[i]);
  float ssum=0.f;
  for (int i=0;i<16;i++) ssum += __expf(st[i]-mx);
  float inv = 1.f/ssum;
  if (t<16) sw[t] = __expf(st[t]-mx)*inv;
  __syncthreads();
  float a=0.f;
  for (int i=0;i<16;i++) a += sw[i]*gld(W2, i*128+t, wf32);
  if (PB) ((unsigned short*)p2)[(size_t)m*DD+t] = f2b(a);
  else    ((float*)p2)[(size_t)m*DD+t] = a;
  if (t<8){
    float bb=0.f;
    for (int i=0;i<16;i++) bb += sw[i]*gld(W1, i*8+t, wf32);
    if (PB) ((unsigned short*)p1)[(size_t)m*HH+t] = f2b(bb);
    else    ((float*)p1)[(size_t)m*HH+t] = bb;
  }
}

__global__ __launch_bounds__(256) void resadd(float* __restrict__ a, const float* __restrict__ b, int n){
  int i = blockIdx.x*256 + threadIdx.x;
  if (i < n) a[i] += b[i];
}

__global__ __launch_bounds__(256) void readout(
    const int* __restrict__ tgt, const int* __restrict__ mnid,
    const unsigned short* __restrict__ featb, const float* __restrict__ p1mn,
    const float* __restrict__ base, float* __restrict__ acc,
    void* __restrict__ out, int last, float invNB, int BT,
    const int* __restrict__ dflag)
{
  int t = blockIdx.x*256 + threadIdx.x;
  if (t >= BT) return;
  int idx = tgt[t]; int mn = mnid[idx];
  float logit = 0.f;
  for (int h=0;h<8;h++){
    float tw = base[h] + p1mn[(size_t)mn*HH + h];
    float srow = 0.f;
    for (int k=0;k<16;k++) srow += b2f(featb[(size_t)idx*DD + h*16 + k]);
    logit += tw*srow;
  }
  if (!last) acc[t] = logit;
  else {
    float r = (acc[t] + logit) * invNB;
    if ((*dflag) != 0) ((float*)out)[t] = r;
    else ((__hip_bfloat16*)out)[t] = __float2bfloat16(r);
  }
}

extern "C" void kernel_launch(void* const* d_in, const int* in_sizes, int n_in,
                              void* d_out, int out_size, void* d_ws, size_t ws_size,
                              hipStream_t stream) {
  const void* emb   = d_in[0];
  const void* u     = d_in[1];
  const void* W2lat = d_in[2];
  const void* W1lat = d_in[3];
  WPtrs wptrs;
  for (int i=0;i<8;i++) wptrs.p[i] = d_in[4+i];
  const int* node_vals      = (const int*)d_in[12];
  const int* meta_node_vals = (const int*)d_in[13];
  const int* src            = (const int*)d_in[14];
  const int* dst            = (const int*)d_in[15];
  const int* meta_src       = (const int*)d_in[16];
  const int* meta_dst       = (const int*)d_in[17];
  const int* meta_node_id   = (const int*)d_in[18];
  const int* meta_edge_id   = (const int*)d_in[19];
  const int* target_idx     = (const int*)d_in[20];
  const int* static_vals    = (const int*)d_in[21];
  const int* static_src     = (const int*)d_in[22];
  const int* static_dst     = (const int*)d_in[23];

  const int N  = in_sizes[12];
  const int MN = in_sizes[13];
  const int E  = in_sizes[14];
  const int ME = in_sizes[16];
  const int BT = in_sizes[20];
  const int NSRC = in_sizes[22];
  const int NB = in_sizes[8] / (DD*DD);

  float* ws = (float*)d_ws;
  size_t off = 0;
  auto allocf = [&](size_t n){ float* p = ws + off; off += n; return p; };
  auto allocb = [&](size_t n){ unsigned short* p = (unsigned short*)(ws + off); off += (n+1)/2; return p; };
  auto alloci = [&](size_t n){ int* p = (int*)(ws + off); off += n; return p; };
  int*            dflag = (int*)ws; off += 4;
  unsigned short* feat  = allocb((size_t)N*DD);
  unsigned short* q     = allocb((size_t)N*DD);
  unsigned short* kv    = allocb((size_t)N*2*DD);   // [node][kf(128) ++ v(128)]
  float*          agg   = allocf((size_t)N*DD);
  float*          z     = allocf((size_t)N*HH);
  float*          meta_feat= allocf((size_t)MN*DD);
  float*          agg_m = allocf((size_t)MN*DD);    // z_m contiguous follows
  float*          z_m   = allocf((size_t)MN*HH);
  unsigned short* q_m   = allocb((size_t)MN*DD);
  unsigned short* kf_m  = allocb((size_t)MN*DD);
  unsigned short* v_m   = allocb((size_t)MN*DD);
  float*          meta_out = allocf((size_t)MN*DD);
  unsigned short* mef   = allocb((size_t)ME*DD);
  float*          p2mn  = allocf((size_t)MN*DD);
  float*          p1mn  = allocf((size_t)MN*HH);
  unsigned short* p2me  = allocb((size_t)ME*DD);
  unsigned short* p1me  = allocb((size_t)ME*HH);
  float*          base  = allocf(280);
  float*          acc   = allocf((size_t)BT);
  unsigned short* wstage= allocb((size_t)8*DD*DD);
  int*            rowptr= alloci((size_t)N+1);
  int*            cursor= alloci((size_t)N);
  int*            deg   = alloci((size_t)N);
  int*            esrc  = alloci((size_t)E);
  int*            emeid = alloci((size_t)E);
  const int nb_scan = (N + 1023)/1024;
  int*            bsum  = alloci((size_t)nb_scan);
  (void)ws_size; (void)n_in; (void)out_size;

  const float* base_n2 = base + 24;

  k_detect<<<1,64,0,stream>>>((const unsigned short*)emb, dflag);
  k_static<<<1,256,0,stream>>>(emb, static_vals, static_src, static_dst,
                               u, W2lat, W1lat, base, NSRC, dflag);
  gather_rows<true ><<<(N*16+255)/256,256,0,stream>>>(emb, node_vals, feat, N, dflag);
  gather_rows<false><<<(MN*16+255)/256,256,0,stream>>>(emb, meta_node_vals, meta_feat, MN, dflag);

  // ---- CSR build (by dst), once per call ----
  zeroi<<<(N+255)/256,256,0,stream>>>(deg, N);
  k_hist<<<(E+255)/256,256,0,stream>>>(dst, deg, E);
  k_scan1<<<nb_scan,256,0,stream>>>(deg, rowptr, bsum, N);
  k_scan2<<<1,64,0,stream>>>(bsum, nb_scan, rowptr, N);
  k_scan3<<<(N+255)/256,256,0,stream>>>(rowptr, bsum, cursor, N);
  k_scatter<<<(E+255)/256,256,0,stream>>>(dst, src, meta_edge_id, cursor, esrc, emeid, E);

  const int gm = (MN+63)/64;
  const int gN = (N+63)/64;
  const long nz_meta = ((long)MN*DD + (long)MN*HH)/4;
  const float invNB = 1.0f/(float)NB;

  for (int b=0;b<NB;b++){
    const size_t bo = (size_t)b*DD*DD;
    w_repack8<<<512,256,0,stream>>>(wptrs, wstage, bo, dflag);
    const unsigned short* wq_m = wstage + 0*DD*DD;
    const unsigned short* wk_m = wstage + 1*DD*DD;
    const unsigned short* wv_m = wstage + 2*DD*DD;
    const unsigned short* wo_m = wstage + 3*DD*DD;
    const unsigned short* wqb  = wstage + 4*DD*DD;
    const unsigned short* wkb  = wstage + 5*DD*DD;
    const unsigned short* wvb  = wstage + 6*DD*DD;
    const unsigned short* wob  = wstage + 7*DD*DD;

    // ---- meta conv (broadcast base params) ----
    gemm_qkv<EPI_SCALE_CONST,false><<<gm,256,0,stream>>>(meta_feat, wq_m, wk_m, wv_m,
        q_m, kf_m, DD, v_m, DD, MN, base_n2, nullptr, nullptr);
    zerof<<<(int)((nz_meta+255)/256),256,0,stream>>>(agg_m, nz_meta);
    edge_meta<<<(ME+3)/4,256,0,stream>>>(meta_src, meta_dst, q_m, kf_m, v_m,
        base, mef, z_m, agg_m, ME);
    gemm128m<EPI_RELU,true,false,false><<<gm,256,0,stream>>>(agg_m, wo_m, meta_out, MN,
        z_m, nullptr, nullptr, nullptr, nullptr);

    // ---- meta learners (pre-residual conv outputs) ----
    learner<false,false><<<MN,128,0,stream>>>(meta_out, u, W2lat, W1lat, p2mn, p1mn, dflag);
    learner<true ,true ><<<ME,128,0,stream>>>(mef,      u, W2lat, W1lat, p2me, p1me, dflag);
    resadd<<<(MN*DD+255)/256,256,0,stream>>>(meta_feat, meta_out, MN*DD);

    // ---- big conv ----
    gemm_qkv<EPI_SCALE_GATHER,true><<<gN,256,0,stream>>>(feat, wqb, wkb, wvb,
        q, kv, 2*DD, kv + DD, 2*DD, N, base_n2, p2mn, meta_node_id);
    edge_fused<<<(N+3)/4,256,0,stream>>>(rowptr, esrc, emeid,
        meta_node_id, q, kv, p2me, p1me, p1mn, base, z, agg, N);
    gemm128m<EPI_RELU_RES,true,false,true><<<gN,256,0,stream>>>(agg, wob, feat, N,
        z, nullptr, nullptr, nullptr, feat);

    // ---- readout ----
    readout<<<(BT+255)/256,256,0,stream>>>(target_idx, meta_node_id, feat, p1mn,
        base, acc, d_out, (b==NB-1) ? 1 : 0, invNB, BT, dflag);
  }
}

// Round 10
// 782.506 us; speedup vs baseline: 1.1379x; 1.0209x over previous
//
#include <hip/hip_runtime.h>
#include <hip/hip_bf16.h>

#define DD   128
#define HH   8

typedef short bf16x8 __attribute__((ext_vector_type(8)));
typedef float f32x4  __attribute__((ext_vector_type(4)));

__device__ __forceinline__ float b2f(unsigned short v){
  union { unsigned int u; float f; } x; x.u = ((unsigned int)v) << 16; return x.f;
}
__device__ __forceinline__ unsigned short f2b(float f){
  __hip_bfloat16 h = __float2bfloat16(f);
  return *(unsigned short*)&h;
}
struct __align__(8) us4 { unsigned short x,y,z,w; };

__device__ __forceinline__ float gld(const void* p, size_t i, bool f32){
  if (f32) return ((const float*)p)[i];
  return b2f(((const unsigned short*)p)[i]);
}

// Detect input float dtype. flag=1 -> inputs are f32.
__global__ __launch_bounds__(64) void k_detect(const unsigned short* __restrict__ emb,
                                               int* __restrict__ flag){
  int t = threadIdx.x;
  float m = 0.f;
  for (int i=t; i<128; i+=64){
    float x = fabsf(b2f(emb[i]));
    if (x < 1e30f) m = fmaxf(m, x);
  }
#pragma unroll
  for (int s=1;s<64;s<<=1) m = fmaxf(m, __shfl_xor(m, s, 64));
  if (t==0) *flag = (m > 1e4f) ? 1 : 0;
}

// All 8 weight blocks -> bf16 TRANSPOSED staging ([n][k]) in one launch.
struct WPtrs { const void* p[8]; };
__global__ __launch_bounds__(256) void w_repack8(
    WPtrs W, unsigned short* __restrict__ stage,
    size_t bo, const int* __restrict__ dflag)
{
  const bool wf32 = (*dflag) != 0;
  int mat = blockIdx.x >> 6;
  int i = (blockIdx.x & 63)*256 + threadIdx.x;
  int k = i >> 7, n = i & 127;
  float x;
  if (wf32) x = ((const float*)W.p[mat])[bo + i];
  else      x = b2f(((const unsigned short*)W.p[mat])[bo + i]);
  stage[(size_t)mat*DD*DD + n*DD + k] = f2b(x);
}

enum { EPI_STORE=0, EPI_SCALE_CONST=1, EPI_SCALE_GATHER=2, EPI_RELU=3,
       EPI_RELU_RES=4, EPI_RELU_RES2=5 };

#define APAD 136   // 128 + 8 bf16: breaks stride-256B bank aliasing
#define CPAD 132   // f32 row pad for epilogue repack

// C[M,128] = epi( prologue(A)[M,128] @ B[128,128] ), B bf16 TRANSPOSED ([n][k]).
// NORM now works for both f32 (INB=0) and bf16 (INB=1) A inputs.
// EPI_RELU_RES : C = relu(x) + Rb(bf16)           [big Wo, OUTB=1]
// EPI_RELU_RES2: Cv = relu(x) f32; C2 = relu(x)+Rf(f32)  [meta Wo, OUTB=0]
template<int EPI, bool NORM, bool INB, bool OUTB>
__global__ __launch_bounds__(256) void gemm128m(
    const void* __restrict__ Av, const unsigned short* __restrict__ Bt,
    void* __restrict__ Cv, int M,
    const float* __restrict__ z, const float* __restrict__ svec,
    const float* __restrict__ P2, const int* __restrict__ gidx,
    const unsigned short* __restrict__ Rb,
    const float* __restrict__ Rf, float* __restrict__ C2)
{
  __shared__ unsigned short Asb[64*APAD];
  __shared__ unsigned short Btb[128*APAD];
  const int tid = threadIdx.x;
  const int wave = tid >> 6, lane = tid & 63;
  const int row0 = blockIdx.x * 64;

  {
    int r = tid >> 2, cb = (tid & 3) * 32;
    int gr = row0 + r;
    if (INB){
      const unsigned short* Ab = (const unsigned short*)Av;
#pragma unroll
      for (int j=0;j<4;j++){
        int c = cb + j*8;
        uint4 raw = make_uint4(0,0,0,0);
        if (gr < M) raw = *(const uint4*)(Ab + (size_t)gr*DD + c);
        if (NORM){
          float s = 0.f;
          if (gr < M) s = 1.0f/(z[(size_t)gr*HH + (c>>4)] + 1e-9f);
          const unsigned short* hw = (const unsigned short*)&raw;
          us4 o0, o1;
          o0.x=f2b(b2f(hw[0])*s); o0.y=f2b(b2f(hw[1])*s);
          o0.z=f2b(b2f(hw[2])*s); o0.w=f2b(b2f(hw[3])*s);
          o1.x=f2b(b2f(hw[4])*s); o1.y=f2b(b2f(hw[5])*s);
          o1.z=f2b(b2f(hw[6])*s); o1.w=f2b(b2f(hw[7])*s);
          *(us4*)&Asb[r*APAD + c] = o0; *(us4*)&Asb[r*APAD + c + 4] = o1;
        } else {
          *(uint4*)&Asb[r*APAD + c] = raw;
        }
      }
    } else {
      const float* Af = (const float*)Av;
#pragma unroll
      for (int j=0;j<8;j++){
        int c = cb + j*4;
        float4 val = make_float4(0.f,0.f,0.f,0.f);
        if (gr < M){
          val = *(const float4*)(Af + (size_t)gr*DD + c);
          if (NORM){
            float s = 1.0f / (z[(size_t)gr*HH + (c>>4)] + 1e-9f);
            val.x*=s; val.y*=s; val.z*=s; val.w*=s;
          }
        }
        us4 o; o.x=f2b(val.x); o.y=f2b(val.y); o.z=f2b(val.z); o.w=f2b(val.w);
        *(us4*)&Asb[r*APAD + c] = o;
      }
    }
  }
  {
    int n = tid >> 1, k0s = (tid & 1) * 64;
#pragma unroll
    for (int j=0;j<8;j++){
      uint4 raw = *(const uint4*)(Bt + (size_t)n*DD + k0s + j*8);
      *(uint4*)&Btb[n*APAD + k0s + j*8] = raw;
    }
  }
  __syncthreads();

  f32x4 acc[8];
#pragma unroll
  for (int t=0;t<8;t++) acc[t] = (f32x4){0.f,0.f,0.f,0.f};
  const int am = (lane & 15), kq = (lane >> 4) * 8;
#pragma unroll
  for (int k0=0;k0<128;k0+=32){
    bf16x8 a = *(bf16x8*)&Asb[(wave*16 + am)*APAD + k0 + kq];
#pragma unroll
    for (int t=0;t<8;t++){
      bf16x8 b = *(bf16x8*)&Btb[(t*16 + am)*APAD + k0 + kq];
      acc[t] = __builtin_amdgcn_mfma_f32_16x16x32_bf16(a, b, acc[t], 0,0,0);
    }
  }
  __syncthreads();
  float* Cls = (float*)Btb;   // [64][CPAD] f32
  {
    int rr = wave*16 + (lane>>4)*4;
    int cc = lane & 15;
#pragma unroll
    for (int t=0;t<8;t++)
#pragma unroll
      for (int r=0;r<4;r++)
        Cls[(rr + r)*CPAD + t*16 + cc] = acc[t][r];
  }
  __syncthreads();

  {
    int r = tid >> 2, cb = (tid & 3) * 32;
    int gr = row0 + r;
    if (gr < M){
#pragma unroll
      for (int j=0;j<8;j++){
        int c = cb + j*4;
        float4 o = *(float4*)&Cls[r*CPAD + c];
        if (EPI == EPI_SCALE_CONST){
          o.x*=svec[c+0]; o.y*=svec[c+1]; o.z*=svec[c+2]; o.w*=svec[c+3];
        } else if (EPI == EPI_SCALE_GATHER){
          int g = gidx[gr];
          const float* p = P2 + (size_t)g*DD + c;
          o.x*=(svec[c+0]+p[0]); o.y*=(svec[c+1]+p[1]);
          o.z*=(svec[c+2]+p[2]); o.w*=(svec[c+3]+p[3]);
        } else if (EPI == EPI_RELU){
          o.x=fmaxf(o.x,0.f); o.y=fmaxf(o.y,0.f); o.z=fmaxf(o.z,0.f); o.w=fmaxf(o.w,0.f);
        } else if (EPI == EPI_RELU_RES){
          us4 rb = *(const us4*)(Rb + (size_t)gr*DD + c);
          o.x=fmaxf(o.x,0.f)+b2f(rb.x); o.y=fmaxf(o.y,0.f)+b2f(rb.y);
          o.z=fmaxf(o.z,0.f)+b2f(rb.z); o.w=fmaxf(o.w,0.f)+b2f(rb.w);
        } else if (EPI == EPI_RELU_RES2){
          o.x=fmaxf(o.x,0.f); o.y=fmaxf(o.y,0.f); o.z=fmaxf(o.z,0.f); o.w=fmaxf(o.w,0.f);
          float4 rf = *(const float4*)(Rf + (size_t)gr*DD + c);
          *(float4*)(C2 + (size_t)gr*DD + c) =
              make_float4(o.x+rf.x, o.y+rf.y, o.z+rf.z, o.w+rf.w);
        }
        if (OUTB){
          us4 ob; ob.x=f2b(o.x); ob.y=f2b(o.y); ob.z=f2b(o.z); ob.w=f2b(o.w);
          *(us4*)((unsigned short*)Cv + (size_t)gr*DD + c) = ob;
        } else {
          *(float4*)((float*)Cv + (size_t)gr*DD + c) = o;
        }
      }
    }
  }
}

// Fused Q/K/V gemm: stage A once, run 3 weight matrices through the same LDS.
template<int EPIQ, bool INB>
__global__ __launch_bounds__(256) void gemm_qkv(
    const void* __restrict__ Av,
    const unsigned short* __restrict__ Btq, const unsigned short* __restrict__ Btk,
    const unsigned short* __restrict__ Btv,
    unsigned short* __restrict__ Cq, unsigned short* __restrict__ Ck, int stK,
    unsigned short* __restrict__ Cvo, int stV, int M,
    const float* __restrict__ svec, const float* __restrict__ P2,
    const int* __restrict__ gidx)
{
  __shared__ unsigned short Asb[64*APAD];
  __shared__ unsigned short Btb[128*APAD];
  const int tid = threadIdx.x;
  const int wave = tid >> 6, lane = tid & 63;
  const int row0 = blockIdx.x * 64;

  {
    int r = tid >> 2, cb = (tid & 3) * 32;
    int gr = row0 + r;
    if (INB){
      const unsigned short* Ab = (const unsigned short*)Av;
#pragma unroll
      for (int j=0;j<4;j++){
        int c = cb + j*8;
        uint4 raw = make_uint4(0,0,0,0);
        if (gr < M) raw = *(const uint4*)(Ab + (size_t)gr*DD + c);
        *(uint4*)&Asb[r*APAD + c] = raw;
      }
    } else {
      const float* Af = (const float*)Av;
#pragma unroll
      for (int j=0;j<8;j++){
        int c = cb + j*4;
        float4 val = make_float4(0.f,0.f,0.f,0.f);
        if (gr < M) val = *(const float4*)(Af + (size_t)gr*DD + c);
        us4 o; o.x=f2b(val.x); o.y=f2b(val.y); o.z=f2b(val.z); o.w=f2b(val.w);
        *(us4*)&Asb[r*APAD + c] = o;
      }
    }
  }

  const unsigned short* Bts[3] = {Btq, Btk, Btv};
  unsigned short* Cs[3] = {Cq, Ck, Cvo};
  const int sts[3] = {DD, stK, stV};
  const int am = (lane & 15), kq = (lane >> 4) * 8;

  for (int ph=0; ph<3; ph++){
    {
      int n = tid >> 1, k0s = (tid & 1) * 64;
      const unsigned short* Bt = Bts[ph];
#pragma unroll
      for (int j=0;j<8;j++){
        uint4 raw = *(const uint4*)(Bt + (size_t)n*DD + k0s + j*8);
        *(uint4*)&Btb[n*APAD + k0s + j*8] = raw;
      }
    }
    __syncthreads();
    f32x4 acc[8];
#pragma unroll
    for (int t=0;t<8;t++) acc[t] = (f32x4){0.f,0.f,0.f,0.f};
#pragma unroll
    for (int k0=0;k0<128;k0+=32){
      bf16x8 a = *(bf16x8*)&Asb[(wave*16 + am)*APAD + k0 + kq];
#pragma unroll
      for (int t=0;t<8;t++){
        bf16x8 b = *(bf16x8*)&Btb[(t*16 + am)*APAD + k0 + kq];
        acc[t] = __builtin_amdgcn_mfma_f32_16x16x32_bf16(a, b, acc[t], 0,0,0);
      }
    }
    __syncthreads();
    float* Cls = (float*)Btb;
    {
      int rr = wave*16 + (lane>>4)*4;
      int cc = lane & 15;
#pragma unroll
      for (int t=0;t<8;t++)
#pragma unroll
        for (int r=0;r<4;r++)
          Cls[(rr + r)*CPAD + t*16 + cc] = acc[t][r];
    }
    __syncthreads();
    {
      int r = tid >> 2, cb = (tid & 3) * 32;
      int gr = row0 + r;
      if (gr < M){
#pragma unroll
        for (int j=0;j<8;j++){
          int c = cb + j*4;
          float4 o = *(float4*)&Cls[r*CPAD + c];
          if (ph == 0){
            if (EPIQ == EPI_SCALE_GATHER){
              int g = gidx[gr];
              const float* p = P2 + (size_t)g*DD + c;
              o.x*=(svec[c+0]+p[0]); o.y*=(svec[c+1]+p[1]);
              o.z*=(svec[c+2]+p[2]); o.w*=(svec[c+3]+p[3]);
            } else { // SCALE_CONST
              o.x*=svec[c+0]; o.y*=svec[c+1]; o.z*=svec[c+2]; o.w*=svec[c+3];
            }
          }
          us4 ob; ob.x=f2b(o.x); ob.y=f2b(o.y); ob.z=f2b(o.z); ob.w=f2b(o.w);
          *(us4*)(Cs[ph] + (size_t)gr*sts[ph] + c) = ob;
        }
      }
    }
    __syncthreads();
  }
}

// Static param-name graph -> base params. base: [0..7]=tw,[8..15]=n1,[16..23]=e1,
// [24..151]=n2,[152..279]=e2
__global__ __launch_bounds__(256) void k_static(
    const void* __restrict__ emb, const int* __restrict__ svals,
    const int* __restrict__ ssrc, const int* __restrict__ sdst,
    const void* __restrict__ u, const void* __restrict__ W2,
    const void* __restrict__ W1, float* __restrict__ base, int nsrc,
    const int* __restrict__ dflag)
{
  __shared__ float sagg[15][128];
  __shared__ float ssc[15][16];
  __shared__ float sww[15][16];
  const bool wf32 = (*dflag) != 0;
  const int t = threadIdx.x;
  for (int i=t;i<15*128;i+=256) ((float*)sagg)[i]=0.f;
  __syncthreads();
  if (t < 128){
    for (int i=0;i<nsrc;i++){
      int row = sdst[i]; int vr = svals[ssrc[i]];
      sagg[row][t] += gld(emb, (size_t)vr*DD + t, wf32);
    }
  }
  __syncthreads();
  if (t < 240){
    int n = t>>4, l = t&15;
    float a=0.f;
    for (int d=0;d<128;d++) a += sagg[n][d]*gld(u, l*128+d, wf32);
    ssc[n][l] = a * 0.08838834764831845f;
  }
  __syncthreads();
  if (t < 15){
    float mx=-1e30f;
    for (int l=0;l<16;l++) mx = fmaxf(mx, ssc[t][l]);
    float s=0.f;
    for (int l=0;l<16;l++){ float e=__expf(ssc[t][l]-mx); sww[t][l]=e; s+=e; }
    float inv = 1.f/s;
    for (int l=0;l<16;l++) sww[t][l]*=inv;
  }
  __syncthreads();
  if (t < 8){
    float a=0.f,b=0.f,c=0.f;
    for (int l=0;l<16;l++){
      float wv = gld(W1, l*8+t, wf32);
      a += sww[0][l]*wv; b += sww[3][l]*wv; c += sww[9][l]*wv;
    }
    base[t]=a; base[8+t]=b; base[16+t]=c;
  }
  if (t < 128){
    float a=0.f,b=0.f;
    for (int l=0;l<16;l++){
      float wv = gld(W2, l*128+t, wf32);
      a += sww[6][l]*wv; b += sww[12][l]*wv;
    }
    base[24+t]=a; base[152+t]=b;
  }
}

template<bool OUTB>
__global__ __launch_bounds__(256) void gather_rows(
    const void* __restrict__ emb, const int* __restrict__ vals,
    void* __restrict__ dstv, int n, const int* __restrict__ dflag)
{
  const bool wf32 = (*dflag) != 0;
  int i = blockIdx.x*256 + threadIdx.x;
  if (i >= n*16) return;
  int r = i>>4, c = (i&15)*8;
  int vr = vals[r];
  float vb[8];
  if (wf32){
    float4 f0 = *(const float4*)((const float*)emb + (size_t)vr*DD + c);
    float4 f1 = *(const float4*)((const float*)emb + (size_t)vr*DD + c + 4);
    vb[0]=f0.x; vb[1]=f0.y; vb[2]=f0.z; vb[3]=f0.w;
    vb[4]=f1.x; vb[5]=f1.y; vb[6]=f1.z; vb[7]=f1.w;
  } else {
    uint4 raw = *(const uint4*)((const unsigned short*)emb + (size_t)vr*DD + c);
    const unsigned short* hw = (const unsigned short*)&raw;
#pragma unroll
    for (int j=0;j<8;j++) vb[j] = b2f(hw[j]);
  }
  if (OUTB){
    unsigned short* d = (unsigned short*)dstv + (size_t)r*DD + c;
    us4 o0, o1;
    o0.x=f2b(vb[0]); o0.y=f2b(vb[1]); o0.z=f2b(vb[2]); o0.w=f2b(vb[3]);
    o1.x=f2b(vb[4]); o1.y=f2b(vb[5]); o1.z=f2b(vb[6]); o1.w=f2b(vb[7]);
    *(us4*)d = o0; *(us4*)(d+4) = o1;
  } else {
    float* d = (float*)dstv + (size_t)r*DD + c;
    *(float4*)d     = make_float4(vb[0],vb[1],vb[2],vb[3]);
    *(float4*)(d+4) = make_float4(vb[4],vb[5],vb[6],vb[7]);
  }
}

__global__ __launch_bounds__(256) void zeroi(int* __restrict__ p, int n){
  int i = blockIdx.x*256 + threadIdx.x;
  if (i < n) p[i] = 0;
}

// ---------------- CSR build (generic, by dst) ----------------
__global__ __launch_bounds__(256) void k_hist(const int* __restrict__ dst,
                                              int* __restrict__ deg, int E){
  int i = blockIdx.x*256 + threadIdx.x;
  if (i < E) atomicAdd(&deg[dst[i]], 1);
}

__global__ __launch_bounds__(256) void k_scan1(const int* __restrict__ deg,
                                               int* __restrict__ rowptr,
                                               int* __restrict__ bsum, int n){
  __shared__ int ls[256];
  int b = blockIdx.x, t = threadIdx.x;
  int base = b*1024 + t*4;
  int v0 = (base+0<n)?deg[base+0]:0;
  int v1 = (base+1<n)?deg[base+1]:0;
  int v2 = (base+2<n)?deg[base+2]:0;
  int v3 = (base+3<n)?deg[base+3]:0;
  int tsum = v0+v1+v2+v3;
  ls[t] = tsum; __syncthreads();
  for (int o=1;o<256;o<<=1){
    int x = (t>=o) ? ls[t-o] : 0;
    __syncthreads();
    ls[t] += x;
    __syncthreads();
  }
  int excl = ls[t]-tsum;
  if (t==255) bsum[b] = ls[255];
  if (base+0<n) rowptr[base+0]=excl;
  if (base+1<n) rowptr[base+1]=excl+v0;
  if (base+2<n) rowptr[base+2]=excl+v0+v1;
  if (base+3<n) rowptr[base+3]=excl+v0+v1+v2;
}

__global__ __launch_bounds__(64) void k_scan2(int* __restrict__ bsum, int nb,
                                              int* __restrict__ rowptr, int n){
  if (threadIdx.x==0){
    int run = 0;
    for (int b=0;b<nb;b++){ int x = bsum[b]; bsum[b] = run; run += x; }
    rowptr[n] = run;
  }
}

__global__ __launch_bounds__(256) void k_scan3(int* __restrict__ rowptr,
                                               const int* __restrict__ bsum,
                                               int* __restrict__ cursor, int n){
  int i = blockIdx.x*256 + threadIdx.x;
  if (i < n){
    int r = rowptr[i] + bsum[i>>10];
    rowptr[i] = r;
    cursor[i] = r;
  }
}

// scatter src + aux into CSR order. aux==nullptr -> store original edge id.
__global__ __launch_bounds__(256) void k_scatter(const int* __restrict__ dst,
                                                 const int* __restrict__ src,
                                                 const int* __restrict__ aux,
                                                 int* __restrict__ cursor,
                                                 int* __restrict__ esrc,
                                                 int* __restrict__ eaux, int E){
  int e = blockIdx.x*256 + threadIdx.x;
  if (e < E){
    int p = atomicAdd(&cursor[dst[e]], 1);
    esrc[p] = src[e];
    eaux[p] = aux ? aux[e] : e;
  }
}

// ---------------- meta-graph edges: CSR, atomic-free, writes mef ----------------
__global__ __launch_bounds__(256) void edge_meta_csr(
    const int* __restrict__ rowptr, const int* __restrict__ esrc,
    const int* __restrict__ eorig,
    const unsigned short* __restrict__ qm, const unsigned short* __restrict__ kfm,
    const unsigned short* __restrict__ vm,
    const float* __restrict__ base, unsigned short* __restrict__ mef,
    float* __restrict__ z, float* __restrict__ agg, int NM)
{
  int d = blockIdx.x*4 + (threadIdx.x>>6);
  if (d >= NM) return;
  int lane = threadIdx.x & 63;
  const float* be2 = base+152; const float* be1 = base+16; const float* bn1 = base+8;
  size_t dq = (size_t)d*DD;
  float q0 = b2f(qm[dq+lane]), q1 = b2f(qm[dq+64+lane]);
  float w0 = be2[lane], w1 = be2[64+lane];
  int h0 = lane>>4, h1 = h0+4;
  float bias0 = be1[h0] + bn1[h0];
  float bias1 = be1[h1] + bn1[h1];
  float z0=0.f, z1=0.f, a0=0.f, a1=0.f;
  int i0 = rowptr[d], i1 = rowptr[d+1];
  for (int i=i0; i<i1; i++){
    int s = esrc[i], e = eorig[i];
    size_t so=(size_t)s*DD, eo=(size_t)e*DD;
    float ke0 = b2f(kfm[so+lane])    * w0;
    float ke1 = b2f(kfm[so+64+lane]) * w1;
    mef[eo+lane]=f2b(ke0); mef[eo+64+lane]=f2b(ke1);
    float p0 = q0*ke0, p1 = q1*ke1;
#pragma unroll
    for (int m=1;m<16;m<<=1){ p0 += __shfl_xor(p0,m,64); p1 += __shfl_xor(p1,m,64); }
    float e0 = __expf(p0*0.25f + bias0);
    float e1 = __expf(p1*0.25f + bias1);
    z0 += e0; z1 += e1;
    a0 += e0*b2f(vm[so+lane]);
    a1 += e1*b2f(vm[so+64+lane]);
  }
  if ((lane&15)==0){ z[(size_t)d*HH+h0] = z0; z[(size_t)d*HH+h1] = z1; }
  agg[dq+lane]    = a0;
  agg[dq+64+lane] = a1;
}

// ---------------- big-graph: fused scores+agg (bf16 agg out) ----------------
__global__ __launch_bounds__(256) void edge_fused(
    const int* __restrict__ rowptr,
    const int* __restrict__ esrc, const int* __restrict__ emeid,
    const int* __restrict__ mnid,
    const unsigned short* __restrict__ q, const unsigned short* __restrict__ kv,
    const unsigned short* __restrict__ w2me, const unsigned short* __restrict__ p1me,
    const float* __restrict__ p1mn, const float* __restrict__ base,
    float* __restrict__ z, unsigned short* __restrict__ aggb, int N)
{
  int d = blockIdx.x*4 + (threadIdx.x>>6);
  if (d >= N) return;
  int lane = threadIdx.x & 63;
  int grp = lane >> 4, l16 = lane & 15;
  int c8 = l16 * 8;
  int h = l16 >> 1;
  size_t dq = (size_t)d*DD;
  const float* be1 = base+16; const float* bn1 = base+8;

  float qv[8];
  {
    uint4 qraw = *(const uint4*)(q + dq + c8);
    const unsigned short* qh = (const unsigned short*)&qraw;
#pragma unroll
    for (int j=0;j<8;j++) qv[j] = b2f(qh[j])*0.25f;   // fold 1/sqrt(16)
  }
  int mn = mnid[d];
  float bias = be1[h] + bn1[h] + p1mn[(size_t)mn*HH + h];

  float zh = 0.f;
  float a[8];
#pragma unroll
  for (int j=0;j<8;j++) a[j] = 0.f;

  int i0 = rowptr[d], i1 = rowptr[d+1];
  int i = i0 + grp;
  for (; i + 4 < i1; i += 8){
    int s0 = esrc[i],   me0 = emeid[i];
    int s1 = esrc[i+4], me1 = emeid[i+4];
    size_t kvo0 = (size_t)s0*(2*DD), mo0 = (size_t)me0*DD;
    size_t kvo1 = (size_t)s1*(2*DD), mo1 = (size_t)me1*DD;
    uint4 kraw0 = *(const uint4*)(kv + kvo0 + c8);
    uint4 vraw0 = *(const uint4*)(kv + kvo0 + DD + c8);
    uint4 wraw0 = *(const uint4*)(w2me + mo0 + c8);
    float pm0 = b2f(p1me[(size_t)me0*HH + h]);
    uint4 kraw1 = *(const uint4*)(kv + kvo1 + c8);
    uint4 vraw1 = *(const uint4*)(kv + kvo1 + DD + c8);
    uint4 wraw1 = *(const uint4*)(w2me + mo1 + c8);
    float pm1 = b2f(p1me[(size_t)me1*HH + h]);
    const unsigned short* kh0 = (const unsigned short*)&kraw0;
    const unsigned short* wh0 = (const unsigned short*)&wraw0;
    const unsigned short* vh0 = (const unsigned short*)&vraw0;
    const unsigned short* kh1 = (const unsigned short*)&kraw1;
    const unsigned short* wh1 = (const unsigned short*)&wraw1;
    const unsigned short* vh1 = (const unsigned short*)&vraw1;
    float pA = 0.f, pB = 0.f;
#pragma unroll
    for (int j=0;j<8;j++){
      pA += qv[j]*(b2f(kh0[j])*b2f(wh0[j]));
      pB += qv[j]*(b2f(kh1[j])*b2f(wh1[j]));
    }
    pA += __shfl_xor(pA, 1, 64);
    pB += __shfl_xor(pB, 1, 64);
    float ex0 = __expf(pA + bias + pm0);
    float ex1 = __expf(pB + bias + pm1);
    zh += ex0 + ex1;
#pragma unroll
    for (int j=0;j<8;j++) a[j] += ex0*b2f(vh0[j]) + ex1*b2f(vh1[j]);
  }
  if (i < i1){
    int s = esrc[i], me = emeid[i];
    size_t kvo = (size_t)s*(2*DD), mo = (size_t)me*DD;
    uint4 kraw = *(const uint4*)(kv + kvo + c8);
    uint4 vraw = *(const uint4*)(kv + kvo + DD + c8);
    uint4 wraw = *(const uint4*)(w2me + mo + c8);
    float pm = b2f(p1me[(size_t)me*HH + h]);
    const unsigned short* kh = (const unsigned short*)&kraw;
    const unsigned short* wh = (const unsigned short*)&wraw;
    const unsigned short* vh = (const unsigned short*)&vraw;
    float p = 0.f;
#pragma unroll
    for (int j=0;j<8;j++) p += qv[j]*(b2f(kh[j])*b2f(wh[j]));
    p += __shfl_xor(p, 1, 64);
    float ex = __expf(p + bias + pm);
    zh += ex;
#pragma unroll
    for (int j=0;j<8;j++) a[j] += ex*b2f(vh[j]);
  }

  zh += __shfl_xor(zh, 16, 64); zh += __shfl_xor(zh, 32, 64);
#pragma unroll
  for (int j=0;j<8;j++){
    a[j] += __shfl_xor(a[j], 16, 64);
    a[j] += __shfl_xor(a[j], 32, 64);
  }
  if (grp == 0){
    us4 o0, o1;
    o0.x=f2b(a[0]); o0.y=f2b(a[1]); o0.z=f2b(a[2]); o0.w=f2b(a[3]);
    o1.x=f2b(a[4]); o1.y=f2b(a[5]); o1.z=f2b(a[6]); o1.w=f2b(a[7]);
    *(us4*)(aggb + dq + c8)     = o0;
    *(us4*)(aggb + dq + c8 + 4) = o1;
    if ((l16 & 1) == 0) z[(size_t)d*HH + h] = zh;
  }
}

// Fused meta-learner over [meta_out (Ma rows, f32) | mef (bf16)].
// ME branch also emits w2me = bf16(base_e2 + p2me).
__global__ __launch_bounds__(128) void learner2(
    const float* __restrict__ Xa, const unsigned short* __restrict__ Xb, int Ma,
    const void* __restrict__ u, const void* __restrict__ W2,
    const void* __restrict__ W1,
    float* __restrict__ p2a, float* __restrict__ p1a,
    unsigned short* __restrict__ w2me, unsigned short* __restrict__ p1b,
    const float* __restrict__ base, const int* __restrict__ dflag)
{
  __shared__ float sX[128];
  __shared__ float st[16];
  __shared__ float sw[16];
  const bool wf32 = (*dflag) != 0;
  const int blk = blockIdx.x, t = threadIdx.x;
  const bool isB = (blk >= Ma);
  const int m = isB ? (blk - Ma) : blk;
  if (isB) sX[t] = b2f(Xb[(size_t)m*DD + t]);
  else     sX[t] = Xa[(size_t)m*DD + t];
  __syncthreads();
  int l = t>>3, j = t&7;
  float part = 0.f;
  for (int d=j*16; d<j*16+16; d++) part += sX[d]*gld(u, l*128+d, wf32);
  part += __shfl_xor(part,1,64); part += __shfl_xor(part,2,64); part += __shfl_xor(part,4,64);
  if (j==0) st[l] = part * 0.08838834764831845f;
  __syncthreads();
  float mx=-1e30f;
  for (int i=0;i<16;i++) mx = fmaxf(mx, st[i]);
  float ssum=0.f;
  for (int i=0;i<16;i++) ssum += __expf(st[i]-mx);
  float inv = 1.f/ssum;
  if (t<16) sw[t] = __expf(st[t]-mx)*inv;
  __syncthreads();
  float a=0.f;
  for (int i=0;i<16;i++) a += sw[i]*gld(W2, i*128+t, wf32);
  if (isB) w2me[(size_t)m*DD+t] = f2b(base[152+t] + a);
  else     p2a[(size_t)m*DD+t] = a;
  if (t<8){
    float bb=0.f;
    for (int i=0;i<16;i++) bb += sw[i]*gld(W1, i*8+t, wf32);
    if (isB) p1b[(size_t)m*HH+t] = f2b(bb);
    else     p1a[(size_t)m*HH+t] = bb;
  }
}

__global__ __launch_bounds__(256) void readout(
    const int* __restrict__ tgt, const int* __restrict__ mnid,
    const unsigned short* __restrict__ featb, const float* __restrict__ p1mn,
    const float* __restrict__ base, float* __restrict__ acc,
    void* __restrict__ out, int last, float invNB, int BT,
    const int* __restrict__ dflag)
{
  int t = blockIdx.x*256 + threadIdx.x;
  if (t >= BT) return;
  int idx = tgt[t]; int mn = mnid[idx];
  float logit = 0.f;
  for (int h=0;h<8;h++){
    float tw = base[h] + p1mn[(size_t)mn*HH + h];
    float srow = 0.f;
    for (int k=0;k<16;k++) srow += b2f(featb[(size_t)idx*DD + h*16 + k]);
    logit += tw*srow;
  }
  if (!last) acc[t] = logit;
  else {
    float r = (acc[t] + logit) * invNB;
    if ((*dflag) != 0) ((float*)out)[t] = r;
    else ((__hip_bfloat16*)out)[t] = __float2bfloat16(r);
  }
}

extern "C" void kernel_launch(void* const* d_in, const int* in_sizes, int n_in,
                              void* d_out, int out_size, void* d_ws, size_t ws_size,
                              hipStream_t stream) {
  const void* emb   = d_in[0];
  const void* u     = d_in[1];
  const void* W2lat = d_in[2];
  const void* W1lat = d_in[3];
  WPtrs wptrs;
  for (int i=0;i<8;i++) wptrs.p[i] = d_in[4+i];
  const int* node_vals      = (const int*)d_in[12];
  const int* meta_node_vals = (const int*)d_in[13];
  const int* src            = (const int*)d_in[14];
  const int* dst            = (const int*)d_in[15];
  const int* meta_src       = (const int*)d_in[16];
  const int* meta_dst       = (const int*)d_in[17];
  const int* meta_node_id   = (const int*)d_in[18];
  const int* meta_edge_id   = (const int*)d_in[19];
  const int* target_idx     = (const int*)d_in[20];
  const int* static_vals    = (const int*)d_in[21];
  const int* static_src     = (const int*)d_in[22];
  const int* static_dst     = (const int*)d_in[23];

  const int N  = in_sizes[12];
  const int MN = in_sizes[13];
  const int E  = in_sizes[14];
  const int ME = in_sizes[16];
  const int BT = in_sizes[20];
  const int NSRC = in_sizes[22];
  const int NB = in_sizes[8] / (DD*DD);

  float* ws = (float*)d_ws;
  size_t off = 0;
  auto allocf = [&](size_t n){ float* p = ws + off; off += n; return p; };
  auto allocb = [&](size_t n){ unsigned short* p = (unsigned short*)(ws + off); off += (n+1)/2; return p; };
  auto alloci = [&](size_t n){ int* p = (int*)(ws + off); off += n; return p; };
  int*            dflag = (int*)ws; off += 4;
  unsigned short* feat  = allocb((size_t)N*DD);
  unsigned short* q     = allocb((size_t)N*DD);
  unsigned short* kv    = allocb((size_t)N*2*DD);   // [node][kf(128) ++ v(128)]
  unsigned short* aggb  = allocb((size_t)N*DD);     // bf16 softmax-weighted sum
  float*          z     = allocf((size_t)N*HH);
  float*          meta_feat= allocf((size_t)MN*DD);
  float*          agg_m = allocf((size_t)MN*DD);
  float*          z_m   = allocf((size_t)MN*HH);
  unsigned short* q_m   = allocb((size_t)MN*DD);
  unsigned short* kf_m  = allocb((size_t)MN*DD);
  unsigned short* v_m   = allocb((size_t)MN*DD);
  float*          meta_out = allocf((size_t)MN*DD);
  unsigned short* mef   = allocb((size_t)ME*DD);
  float*          p2mn  = allocf((size_t)MN*DD);
  float*          p1mn  = allocf((size_t)MN*HH);
  unsigned short* w2me  = allocb((size_t)ME*DD);
  unsigned short* p1me  = allocb((size_t)ME*HH);
  float*          base  = allocf(280);
  float*          acc   = allocf((size_t)BT);
  unsigned short* wstage= allocb((size_t)8*DD*DD);
  // big-graph CSR
  int*            rowptr= alloci((size_t)N+1);
  int*            cursor= alloci((size_t)N);
  int*            deg   = alloci((size_t)N);
  int*            esrc  = alloci((size_t)E);
  int*            emeid = alloci((size_t)E);
  const int nb_scan = (N + 1023)/1024;
  int*            bsum  = alloci((size_t)nb_scan);
  // meta-graph CSR
  int*            rowptr_m= alloci((size_t)MN+1);
  int*            cursor_m= alloci((size_t)MN);
  int*            deg_m   = alloci((size_t)MN);
  int*            esrc_m  = alloci((size_t)ME);
  int*            eorig_m = alloci((size_t)ME);
  const int nb_scan_m = (MN + 1023)/1024;
  int*            bsum_m  = alloci((size_t)nb_scan_m);
  (void)ws_size; (void)n_in; (void)out_size;

  const float* base_n2 = base + 24;

  k_detect<<<1,64,0,stream>>>((const unsigned short*)emb, dflag);
  k_static<<<1,256,0,stream>>>(emb, static_vals, static_src, static_dst,
                               u, W2lat, W1lat, base, NSRC, dflag);
  gather_rows<true ><<<(N*16+255)/256,256,0,stream>>>(emb, node_vals, feat, N, dflag);
  gather_rows<false><<<(MN*16+255)/256,256,0,stream>>>(emb, meta_node_vals, meta_feat, MN, dflag);

  // ---- CSR builds (once per call) ----
  zeroi<<<(N+255)/256,256,0,stream>>>(deg, N);
  k_hist<<<(E+255)/256,256,0,stream>>>(dst, deg, E);
  k_scan1<<<nb_scan,256,0,stream>>>(deg, rowptr, bsum, N);
  k_scan2<<<1,64,0,stream>>>(bsum, nb_scan, rowptr, N);
  k_scan3<<<(N+255)/256,256,0,stream>>>(rowptr, bsum, cursor, N);
  k_scatter<<<(E+255)/256,256,0,stream>>>(dst, src, meta_edge_id, cursor, esrc, emeid, E);

  zeroi<<<(MN+255)/256,256,0,stream>>>(deg_m, MN);
  k_hist<<<(ME+255)/256,256,0,stream>>>(meta_dst, deg_m, ME);
  k_scan1<<<nb_scan_m,256,0,stream>>>(deg_m, rowptr_m, bsum_m, MN);
  k_scan2<<<1,64,0,stream>>>(bsum_m, nb_scan_m, rowptr_m, MN);
  k_scan3<<<(MN+255)/256,256,0,stream>>>(rowptr_m, bsum_m, cursor_m, MN);
  k_scatter<<<(ME+255)/256,256,0,stream>>>(meta_dst, meta_src, nullptr, cursor_m,
                                           esrc_m, eorig_m, ME);

  const int gm = (MN+63)/64;
  const int gN = (N+63)/64;
  const float invNB = 1.0f/(float)NB;

  for (int b=0;b<NB;b++){
    const size_t bo = (size_t)b*DD*DD;
    w_repack8<<<512,256,0,stream>>>(wptrs, wstage, bo, dflag);
    const unsigned short* wq_m = wstage + 0*DD*DD;
    const unsigned short* wk_m = wstage + 1*DD*DD;
    const unsigned short* wv_m = wstage + 2*DD*DD;
    const unsigned short* wo_m = wstage + 3*DD*DD;
    const unsigned short* wqb  = wstage + 4*DD*DD;
    const unsigned short* wkb  = wstage + 5*DD*DD;
    const unsigned short* wvb  = wstage + 6*DD*DD;
    const unsigned short* wob  = wstage + 7*DD*DD;

    // ---- meta conv (broadcast base params; CSR, atomic-free) ----
    gemm_qkv<EPI_SCALE_CONST,false><<<gm,256,0,stream>>>(meta_feat, wq_m, wk_m, wv_m,
        q_m, kf_m, DD, v_m, DD, MN, base_n2, nullptr, nullptr);
    edge_meta_csr<<<(MN+3)/4,256,0,stream>>>(rowptr_m, esrc_m, eorig_m,
        q_m, kf_m, v_m, base, mef, z_m, agg_m, MN);
    // meta Wo: meta_out = relu(norm(agg_m)@Wo); meta_feat += relu(...)
    gemm128m<EPI_RELU_RES2,true,false,false><<<gm,256,0,stream>>>(agg_m, wo_m,
        meta_out, MN, z_m, nullptr, nullptr, nullptr, nullptr, meta_feat, meta_feat);

    // ---- fused meta learners (pre-residual conv outputs) ----
    learner2<<<MN+ME,128,0,stream>>>(meta_out, mef, MN, u, W2lat, W1lat,
        p2mn, p1mn, w2me, p1me, base, dflag);

    // ---- big conv ----
    gemm_qkv<EPI_SCALE_GATHER,true><<<gN,256,0,stream>>>(feat, wqb, wkb, wvb,
        q, kv, 2*DD, kv + DD, 2*DD, N, base_n2, p2mn, meta_node_id);
    edge_fused<<<(N+3)/4,256,0,stream>>>(rowptr, esrc, emeid,
        meta_node_id, q, kv, w2me, p1me, p1mn, base, z, aggb, N);
    gemm128m<EPI_RELU_RES,true,true,true><<<gN,256,0,stream>>>(aggb, wob, feat, N,
        z, nullptr, nullptr, nullptr, feat, nullptr, nullptr);

    // ---- readout ----
    readout<<<(BT+255)/256,256,0,stream>>>(target_idx, meta_node_id, feat, p1mn,
        base, acc, d_out, (b==NB-1) ? 1 : 0, invNB, BT, dflag);
  }
}

// Round 11
// 773.256 us; speedup vs baseline: 1.1515x; 1.0120x over previous
//
#include <hip/hip_runtime.h>
#include <hip/hip_bf16.h>

#define DD   128
#define HH   8

typedef short bf16x8 __attribute__((ext_vector_type(8)));
typedef float f32x4  __attribute__((ext_vector_type(4)));

__device__ __forceinline__ float b2f(unsigned short v){
  union { unsigned int u; float f; } x; x.u = ((unsigned int)v) << 16; return x.f;
}
__device__ __forceinline__ unsigned short f2b(float f){
  __hip_bfloat16 h = __float2bfloat16(f);
  return *(unsigned short*)&h;
}
struct __align__(8) us4 { unsigned short x,y,z,w; };

__device__ __forceinline__ float gld(const void* p, size_t i, bool f32){
  if (f32) return ((const float*)p)[i];
  return b2f(((const unsigned short*)p)[i]);
}

// Detect input float dtype. flag=1 -> inputs are f32.
__global__ __launch_bounds__(64) void k_detect(const unsigned short* __restrict__ emb,
                                               int* __restrict__ flag){
  int t = threadIdx.x;
  float m = 0.f;
  for (int i=t; i<128; i+=64){
    float x = fabsf(b2f(emb[i]));
    if (x < 1e30f) m = fmaxf(m, x);
  }
#pragma unroll
  for (int s=1;s<64;s<<=1) m = fmaxf(m, __shfl_xor(m, s, 64));
  if (t==0) *flag = (m > 1e4f) ? 1 : 0;
}

// ALL weight blocks (8 tensors x NB matrices) -> bf16 TRANSPOSED staging, one launch.
struct WPtrs { const void* p[8]; };
__global__ __launch_bounds__(256) void w_repack16(
    WPtrs W, unsigned short* __restrict__ stage, int NBt,
    const int* __restrict__ dflag)
{
  const bool wf32 = (*dflag) != 0;
  int idx = blockIdx.x >> 6;            // 0 .. 8*NBt-1
  int ti = idx / NBt, bi = idx - ti*NBt;
  size_t bo = (size_t)bi*DD*DD;
  int i = (blockIdx.x & 63)*256 + threadIdx.x;
  int k = i >> 7, n = i & 127;
  float x;
  if (wf32) x = ((const float*)W.p[ti])[bo + i];
  else      x = b2f(((const unsigned short*)W.p[ti])[bo + i]);
  stage[(size_t)idx*DD*DD + n*DD + k] = f2b(x);
}

enum { EPI_STORE=0, EPI_SCALE_CONST=1, EPI_SCALE_GATHER=2, EPI_RELU=3,
       EPI_RELU_RES=4, EPI_RELU_RES2=5 };

#define APAD 136
#define CPAD 132

// C[M,128] = epi( prologue(A)[M,128] @ B[128,128] ), B bf16 TRANSPOSED ([n][k]).
template<int EPI, bool NORM, bool INB, bool OUTB>
__global__ __launch_bounds__(256) void gemm128m(
    const void* __restrict__ Av, const unsigned short* __restrict__ Bt,
    void* __restrict__ Cv, int M,
    const float* __restrict__ z, const float* __restrict__ svec,
    const float* __restrict__ P2, const int* __restrict__ gidx,
    const unsigned short* __restrict__ Rb,
    const float* __restrict__ Rf, float* __restrict__ C2)
{
  __shared__ unsigned short Asb[64*APAD];
  __shared__ unsigned short Btb[128*APAD];
  const int tid = threadIdx.x;
  const int wave = tid >> 6, lane = tid & 63;
  const int row0 = blockIdx.x * 64;

  {
    int r = tid >> 2, cb = (tid & 3) * 32;
    int gr = row0 + r;
    if (INB){
      const unsigned short* Ab = (const unsigned short*)Av;
#pragma unroll
      for (int j=0;j<4;j++){
        int c = cb + j*8;
        uint4 raw = make_uint4(0,0,0,0);
        if (gr < M) raw = *(const uint4*)(Ab + (size_t)gr*DD + c);
        if (NORM){
          float s = 0.f;
          if (gr < M) s = 1.0f/(z[(size_t)gr*HH + (c>>4)] + 1e-9f);
          const unsigned short* hw = (const unsigned short*)&raw;
          us4 o0, o1;
          o0.x=f2b(b2f(hw[0])*s); o0.y=f2b(b2f(hw[1])*s);
          o0.z=f2b(b2f(hw[2])*s); o0.w=f2b(b2f(hw[3])*s);
          o1.x=f2b(b2f(hw[4])*s); o1.y=f2b(b2f(hw[5])*s);
          o1.z=f2b(b2f(hw[6])*s); o1.w=f2b(b2f(hw[7])*s);
          *(us4*)&Asb[r*APAD + c] = o0; *(us4*)&Asb[r*APAD + c + 4] = o1;
        } else {
          *(uint4*)&Asb[r*APAD + c] = raw;
        }
      }
    } else {
      const float* Af = (const float*)Av;
#pragma unroll
      for (int j=0;j<8;j++){
        int c = cb + j*4;
        float4 val = make_float4(0.f,0.f,0.f,0.f);
        if (gr < M){
          val = *(const float4*)(Af + (size_t)gr*DD + c);
          if (NORM){
            float s = 1.0f / (z[(size_t)gr*HH + (c>>4)] + 1e-9f);
            val.x*=s; val.y*=s; val.z*=s; val.w*=s;
          }
        }
        us4 o; o.x=f2b(val.x); o.y=f2b(val.y); o.z=f2b(val.z); o.w=f2b(val.w);
        *(us4*)&Asb[r*APAD + c] = o;
      }
    }
  }
  {
    int n = tid >> 1, k0s = (tid & 1) * 64;
#pragma unroll
    for (int j=0;j<8;j++){
      uint4 raw = *(const uint4*)(Bt + (size_t)n*DD + k0s + j*8);
      *(uint4*)&Btb[n*APAD + k0s + j*8] = raw;
    }
  }
  __syncthreads();

  f32x4 acc[8];
#pragma unroll
  for (int t=0;t<8;t++) acc[t] = (f32x4){0.f,0.f,0.f,0.f};
  const int am = (lane & 15), kq = (lane >> 4) * 8;
#pragma unroll
  for (int k0=0;k0<128;k0+=32){
    bf16x8 a = *(bf16x8*)&Asb[(wave*16 + am)*APAD + k0 + kq];
#pragma unroll
    for (int t=0;t<8;t++){
      bf16x8 b = *(bf16x8*)&Btb[(t*16 + am)*APAD + k0 + kq];
      acc[t] = __builtin_amdgcn_mfma_f32_16x16x32_bf16(a, b, acc[t], 0,0,0);
    }
  }
  __syncthreads();
  float* Cls = (float*)Btb;
  {
    int rr = wave*16 + (lane>>4)*4;
    int cc = lane & 15;
#pragma unroll
    for (int t=0;t<8;t++)
#pragma unroll
      for (int r=0;r<4;r++)
        Cls[(rr + r)*CPAD + t*16 + cc] = acc[t][r];
  }
  __syncthreads();

  {
    int r = tid >> 2, cb = (tid & 3) * 32;
    int gr = row0 + r;
    if (gr < M){
#pragma unroll
      for (int j=0;j<8;j++){
        int c = cb + j*4;
        float4 o = *(float4*)&Cls[r*CPAD + c];
        if (EPI == EPI_SCALE_CONST){
          o.x*=svec[c+0]; o.y*=svec[c+1]; o.z*=svec[c+2]; o.w*=svec[c+3];
        } else if (EPI == EPI_SCALE_GATHER){
          int g = gidx[gr];
          const float* p = P2 + (size_t)g*DD + c;
          o.x*=(svec[c+0]+p[0]); o.y*=(svec[c+1]+p[1]);
          o.z*=(svec[c+2]+p[2]); o.w*=(svec[c+3]+p[3]);
        } else if (EPI == EPI_RELU){
          o.x=fmaxf(o.x,0.f); o.y=fmaxf(o.y,0.f); o.z=fmaxf(o.z,0.f); o.w=fmaxf(o.w,0.f);
        } else if (EPI == EPI_RELU_RES){
          us4 rb = *(const us4*)(Rb + (size_t)gr*DD + c);
          o.x=fmaxf(o.x,0.f)+b2f(rb.x); o.y=fmaxf(o.y,0.f)+b2f(rb.y);
          o.z=fmaxf(o.z,0.f)+b2f(rb.z); o.w=fmaxf(o.w,0.f)+b2f(rb.w);
        } else if (EPI == EPI_RELU_RES2){
          o.x=fmaxf(o.x,0.f); o.y=fmaxf(o.y,0.f); o.z=fmaxf(o.z,0.f); o.w=fmaxf(o.w,0.f);
          float4 rf = *(const float4*)(Rf + (size_t)gr*DD + c);
          *(float4*)(C2 + (size_t)gr*DD + c) =
              make_float4(o.x+rf.x, o.y+rf.y, o.z+rf.z, o.w+rf.w);
        }
        if (OUTB){
          us4 ob; ob.x=f2b(o.x); ob.y=f2b(o.y); ob.z=f2b(o.z); ob.w=f2b(o.w);
          *(us4*)((unsigned short*)Cv + (size_t)gr*DD + c) = ob;
        } else {
          *(float4*)((float*)Cv + (size_t)gr*DD + c) = o;
        }
      }
    }
  }
}

// Fused Q/K/V gemm: stage A once, run 3 weight matrices through the same LDS.
template<int EPIQ, bool INB>
__global__ __launch_bounds__(256) void gemm_qkv(
    const void* __restrict__ Av,
    const unsigned short* __restrict__ Btq, const unsigned short* __restrict__ Btk,
    const unsigned short* __restrict__ Btv,
    unsigned short* __restrict__ Cq, unsigned short* __restrict__ Ck, int stK,
    unsigned short* __restrict__ Cvo, int stV, int M,
    const float* __restrict__ svec, const float* __restrict__ P2,
    const int* __restrict__ gidx)
{
  __shared__ unsigned short Asb[64*APAD];
  __shared__ unsigned short Btb[128*APAD];
  const int tid = threadIdx.x;
  const int wave = tid >> 6, lane = tid & 63;
  const int row0 = blockIdx.x * 64;

  {
    int r = tid >> 2, cb = (tid & 3) * 32;
    int gr = row0 + r;
    if (INB){
      const unsigned short* Ab = (const unsigned short*)Av;
#pragma unroll
      for (int j=0;j<4;j++){
        int c = cb + j*8;
        uint4 raw = make_uint4(0,0,0,0);
        if (gr < M) raw = *(const uint4*)(Ab + (size_t)gr*DD + c);
        *(uint4*)&Asb[r*APAD + c] = raw;
      }
    } else {
      const float* Af = (const float*)Av;
#pragma unroll
      for (int j=0;j<8;j++){
        int c = cb + j*4;
        float4 val = make_float4(0.f,0.f,0.f,0.f);
        if (gr < M) val = *(const float4*)(Af + (size_t)gr*DD + c);
        us4 o; o.x=f2b(val.x); o.y=f2b(val.y); o.z=f2b(val.z); o.w=f2b(val.w);
        *(us4*)&Asb[r*APAD + c] = o;
      }
    }
  }

  const unsigned short* Bts[3] = {Btq, Btk, Btv};
  unsigned short* Cs[3] = {Cq, Ck, Cvo};
  const int sts[3] = {DD, stK, stV};
  const int am = (lane & 15), kq = (lane >> 4) * 8;

  for (int ph=0; ph<3; ph++){
    {
      int n = tid >> 1, k0s = (tid & 1) * 64;
      const unsigned short* Bt = Bts[ph];
#pragma unroll
      for (int j=0;j<8;j++){
        uint4 raw = *(const uint4*)(Bt + (size_t)n*DD + k0s + j*8);
        *(uint4*)&Btb[n*APAD + k0s + j*8] = raw;
      }
    }
    __syncthreads();
    f32x4 acc[8];
#pragma unroll
    for (int t=0;t<8;t++) acc[t] = (f32x4){0.f,0.f,0.f,0.f};
#pragma unroll
    for (int k0=0;k0<128;k0+=32){
      bf16x8 a = *(bf16x8*)&Asb[(wave*16 + am)*APAD + k0 + kq];
#pragma unroll
      for (int t=0;t<8;t++){
        bf16x8 b = *(bf16x8*)&Btb[(t*16 + am)*APAD + k0 + kq];
        acc[t] = __builtin_amdgcn_mfma_f32_16x16x32_bf16(a, b, acc[t], 0,0,0);
      }
    }
    __syncthreads();
    float* Cls = (float*)Btb;
    {
      int rr = wave*16 + (lane>>4)*4;
      int cc = lane & 15;
#pragma unroll
      for (int t=0;t<8;t++)
#pragma unroll
        for (int r=0;r<4;r++)
          Cls[(rr + r)*CPAD + t*16 + cc] = acc[t][r];
    }
    __syncthreads();
    {
      int r = tid >> 2, cb = (tid & 3) * 32;
      int gr = row0 + r;
      if (gr < M){
#pragma unroll
        for (int j=0;j<8;j++){
          int c = cb + j*4;
          float4 o = *(float4*)&Cls[r*CPAD + c];
          if (ph == 0){
            if (EPIQ == EPI_SCALE_GATHER){
              int g = gidx[gr];
              const float* p = P2 + (size_t)g*DD + c;
              o.x*=(svec[c+0]+p[0]); o.y*=(svec[c+1]+p[1]);
              o.z*=(svec[c+2]+p[2]); o.w*=(svec[c+3]+p[3]);
            } else {
              o.x*=svec[c+0]; o.y*=svec[c+1]; o.z*=svec[c+2]; o.w*=svec[c+3];
            }
          }
          us4 ob; ob.x=f2b(o.x); ob.y=f2b(o.y); ob.z=f2b(o.z); ob.w=f2b(o.w);
          *(us4*)(Cs[ph] + (size_t)gr*sts[ph] + c) = ob;
        }
      }
    }
    __syncthreads();
  }
}

// Static param-name graph -> base params.
__global__ __launch_bounds__(256) void k_static(
    const void* __restrict__ emb, const int* __restrict__ svals,
    const int* __restrict__ ssrc, const int* __restrict__ sdst,
    const void* __restrict__ u, const void* __restrict__ W2,
    const void* __restrict__ W1, float* __restrict__ base, int nsrc,
    const int* __restrict__ dflag)
{
  __shared__ float sagg[15][128];
  __shared__ float ssc[15][16];
  __shared__ float sww[15][16];
  const bool wf32 = (*dflag) != 0;
  const int t = threadIdx.x;
  for (int i=t;i<15*128;i+=256) ((float*)sagg)[i]=0.f;
  __syncthreads();
  if (t < 128){
    for (int i=0;i<nsrc;i++){
      int row = sdst[i]; int vr = svals[ssrc[i]];
      sagg[row][t] += gld(emb, (size_t)vr*DD + t, wf32);
    }
  }
  __syncthreads();
  if (t < 240){
    int n = t>>4, l = t&15;
    float a=0.f;
    for (int d=0;d<128;d++) a += sagg[n][d]*gld(u, l*128+d, wf32);
    ssc[n][l] = a * 0.08838834764831845f;
  }
  __syncthreads();
  if (t < 15){
    float mx=-1e30f;
    for (int l=0;l<16;l++) mx = fmaxf(mx, ssc[t][l]);
    float s=0.f;
    for (int l=0;l<16;l++){ float e=__expf(ssc[t][l]-mx); sww[t][l]=e; s+=e; }
    float inv = 1.f/s;
    for (int l=0;l<16;l++) sww[t][l]*=inv;
  }
  __syncthreads();
  if (t < 8){
    float a=0.f,b=0.f,c=0.f;
    for (int l=0;l<16;l++){
      float wv = gld(W1, l*8+t, wf32);
      a += sww[0][l]*wv; b += sww[3][l]*wv; c += sww[9][l]*wv;
    }
    base[t]=a; base[8+t]=b; base[16+t]=c;
  }
  if (t < 128){
    float a=0.f,b=0.f;
    for (int l=0;l<16;l++){
      float wv = gld(W2, l*128+t, wf32);
      a += sww[6][l]*wv; b += sww[12][l]*wv;
    }
    base[24+t]=a; base[152+t]=b;
  }
}

// Merged gather: big graph rows -> bf16 feat; meta rows -> f32 meta_feat.
__global__ __launch_bounds__(256) void gather_rows2(
    const void* __restrict__ emb,
    const int* __restrict__ valsB, unsigned short* __restrict__ featB, int nB,
    const int* __restrict__ valsM, float* __restrict__ featM, int nM,
    const int* __restrict__ dflag)
{
  const bool wf32 = (*dflag) != 0;
  int i = blockIdx.x*256 + threadIdx.x;
  bool big = (i < nB*16);
  int i2 = big ? i : (i - nB*16);
  if (!big && i2 >= nM*16) return;
  int r = i2>>4, c = (i2&15)*8;
  int vr = big ? valsB[r] : valsM[r];
  float vb[8];
  if (wf32){
    float4 f0 = *(const float4*)((const float*)emb + (size_t)vr*DD + c);
    float4 f1 = *(const float4*)((const float*)emb + (size_t)vr*DD + c + 4);
    vb[0]=f0.x; vb[1]=f0.y; vb[2]=f0.z; vb[3]=f0.w;
    vb[4]=f1.x; vb[5]=f1.y; vb[6]=f1.z; vb[7]=f1.w;
  } else {
    uint4 raw = *(const uint4*)((const unsigned short*)emb + (size_t)vr*DD + c);
    const unsigned short* hw = (const unsigned short*)&raw;
#pragma unroll
    for (int j=0;j<8;j++) vb[j] = b2f(hw[j]);
  }
  if (big){
    unsigned short* d = featB + (size_t)r*DD + c;
    us4 o0, o1;
    o0.x=f2b(vb[0]); o0.y=f2b(vb[1]); o0.z=f2b(vb[2]); o0.w=f2b(vb[3]);
    o1.x=f2b(vb[4]); o1.y=f2b(vb[5]); o1.z=f2b(vb[6]); o1.w=f2b(vb[7]);
    *(us4*)d = o0; *(us4*)(d+4) = o1;
  } else {
    float* d = featM + (size_t)r*DD + c;
    *(float4*)d     = make_float4(vb[0],vb[1],vb[2],vb[3]);
    *(float4*)(d+4) = make_float4(vb[4],vb[5],vb[6],vb[7]);
  }
}

__global__ __launch_bounds__(256) void zeroi(int* __restrict__ p, int n){
  int i = blockIdx.x*256 + threadIdx.x;
  if (i < n) p[i] = 0;
}

// ---------------- merged CSR build (big + meta graphs) ----------------
__global__ __launch_bounds__(256) void k_hist2(
    const int* __restrict__ dstB, const int* __restrict__ dstM,
    int* __restrict__ degB, int* __restrict__ degM, int E, int ME, int nbE){
  int b = blockIdx.x, t = threadIdx.x;
  if (b < nbE){ int i = b*256+t; if (i < E) atomicAdd(&degB[dstB[i]], 1); }
  else { int i = (b-nbE)*256+t; if (i < ME) atomicAdd(&degM[dstM[i]], 1); }
}

__global__ __launch_bounds__(256) void k_scan1b(
    const int* __restrict__ degB, int* __restrict__ rpB, int* __restrict__ bsB,
    int nB, int nbB,
    const int* __restrict__ degM, int* __restrict__ rpM, int* __restrict__ bsM,
    int nM){
  __shared__ int ls[256];
  int blk = blockIdx.x, t = threadIdx.x;
  const int* deg; int* rowptr; int* bsum; int n; int b;
  if (blk < nbB){ deg=degB; rowptr=rpB; bsum=bsB; n=nB; b=blk; }
  else          { deg=degM; rowptr=rpM; bsum=bsM; n=nM; b=blk-nbB; }
  int base = b*1024 + t*4;
  int v0 = (base+0<n)?deg[base+0]:0;
  int v1 = (base+1<n)?deg[base+1]:0;
  int v2 = (base+2<n)?deg[base+2]:0;
  int v3 = (base+3<n)?deg[base+3]:0;
  int tsum = v0+v1+v2+v3;
  ls[t] = tsum; __syncthreads();
  for (int o=1;o<256;o<<=1){
    int x = (t>=o) ? ls[t-o] : 0;
    __syncthreads();
    ls[t] += x;
    __syncthreads();
  }
  int excl = ls[t]-tsum;
  if (t==255) bsum[b] = ls[255];
  if (base+0<n) rowptr[base+0]=excl;
  if (base+1<n) rowptr[base+1]=excl+v0;
  if (base+2<n) rowptr[base+2]=excl+v0+v1;
  if (base+3<n) rowptr[base+3]=excl+v0+v1+v2;
}

__global__ __launch_bounds__(64) void k_scan2b(
    int* __restrict__ bsB, int nbB, int* __restrict__ rpB, int nB,
    int* __restrict__ bsM, int nbM, int* __restrict__ rpM, int nM){
  int t = threadIdx.x;
  if (t == 0){
    int run = 0;
    for (int b=0;b<nbB;b++){ int x = bsB[b]; bsB[b] = run; run += x; }
    rpB[nB] = run;
  } else if (t == 1){
    int run = 0;
    for (int b=0;b<nbM;b++){ int x = bsM[b]; bsM[b] = run; run += x; }
    rpM[nM] = run;
  }
}

__global__ __launch_bounds__(256) void k_scan3b(
    int* __restrict__ rpB, const int* __restrict__ bsB, int* __restrict__ curB,
    int nB, int nb3B,
    int* __restrict__ rpM, const int* __restrict__ bsM, int* __restrict__ curM,
    int nM){
  int blk = blockIdx.x, t = threadIdx.x;
  if (blk < nb3B){
    int i = blk*256 + t;
    if (i < nB){ int r = rpB[i] + bsB[i>>10]; rpB[i] = r; curB[i] = r; }
  } else {
    int i = (blk-nb3B)*256 + t;
    if (i < nM){ int r = rpM[i] + bsM[i>>10]; rpM[i] = r; curM[i] = r; }
  }
}

__global__ __launch_bounds__(256) void k_scatter2(
    const int* __restrict__ dstB, const int* __restrict__ srcB,
    const int* __restrict__ auxB, int* __restrict__ curB,
    int* __restrict__ esrcB, int* __restrict__ eauxB, int E, int nbE,
    const int* __restrict__ dstM, const int* __restrict__ srcM,
    int* __restrict__ curM, int* __restrict__ esrcM, int* __restrict__ eauxM,
    int ME){
  int blk = blockIdx.x, t = threadIdx.x;
  if (blk < nbE){
    int e = blk*256 + t;
    if (e < E){
      int p = atomicAdd(&curB[dstB[e]], 1);
      esrcB[p] = srcB[e];
      eauxB[p] = auxB[e];
    }
  } else {
    int e = (blk-nbE)*256 + t;
    if (e < ME){
      int p = atomicAdd(&curM[dstM[e]], 1);
      esrcM[p] = srcM[e];
      eauxM[p] = e;
    }
  }
}

// ---------------- meta-graph edges: CSR, atomic-free, writes mef ----------------
__global__ __launch_bounds__(256) void edge_meta_csr(
    const int* __restrict__ rowptr, const int* __restrict__ esrc,
    const int* __restrict__ eorig,
    const unsigned short* __restrict__ qm, const unsigned short* __restrict__ kfm,
    const unsigned short* __restrict__ vm,
    const float* __restrict__ base, unsigned short* __restrict__ mef,
    float* __restrict__ z, float* __restrict__ agg, int NM)
{
  int d = blockIdx.x*4 + (threadIdx.x>>6);
  if (d >= NM) return;
  int lane = threadIdx.x & 63;
  const float* be2 = base+152; const float* be1 = base+16; const float* bn1 = base+8;
  size_t dq = (size_t)d*DD;
  float q0 = b2f(qm[dq+lane]), q1 = b2f(qm[dq+64+lane]);
  float w0 = be2[lane], w1 = be2[64+lane];
  int h0 = lane>>4, h1 = h0+4;
  float bias0 = be1[h0] + bn1[h0];
  float bias1 = be1[h1] + bn1[h1];
  float z0=0.f, z1=0.f, a0=0.f, a1=0.f;
  int i0 = rowptr[d], i1 = rowptr[d+1];
  for (int i=i0; i<i1; i++){
    int s = esrc[i], e = eorig[i];
    size_t so=(size_t)s*DD, eo=(size_t)e*DD;
    float ke0 = b2f(kfm[so+lane])    * w0;
    float ke1 = b2f(kfm[so+64+lane]) * w1;
    mef[eo+lane]=f2b(ke0); mef[eo+64+lane]=f2b(ke1);
    float p0 = q0*ke0, p1 = q1*ke1;
#pragma unroll
    for (int m=1;m<16;m<<=1){ p0 += __shfl_xor(p0,m,64); p1 += __shfl_xor(p1,m,64); }
    float e0 = __expf(p0*0.25f + bias0);
    float e1 = __expf(p1*0.25f + bias1);
    z0 += e0; z1 += e1;
    a0 += e0*b2f(vm[so+lane]);
    a1 += e1*b2f(vm[so+64+lane]);
  }
  if ((lane&15)==0){ z[(size_t)d*HH+h0] = z0; z[(size_t)d*HH+h1] = z1; }
  agg[dq+lane]    = a0;
  agg[dq+64+lane] = a1;
}

// ---------------- big-graph: fused scores+agg, 4 dsts per wave ----------------
__global__ __launch_bounds__(256) void edge_fused(
    const int* __restrict__ rowptr,
    const int* __restrict__ esrc, const int* __restrict__ emeid,
    const int* __restrict__ mnid,
    const unsigned short* __restrict__ q, const unsigned short* __restrict__ kv,
    const unsigned short* __restrict__ w2me, const unsigned short* __restrict__ p1me,
    const float* __restrict__ p1mn, const float* __restrict__ base,
    float* __restrict__ z, unsigned short* __restrict__ aggb, int N)
{
  int wv = blockIdx.x*4 + (threadIdx.x>>6);
  int d0 = wv*4;
  if (d0 >= N) return;
  int lane = threadIdx.x & 63;
  int grp = lane >> 4, l16 = lane & 15;
  int c8 = l16 * 8;
  int h = l16 >> 1;
  const float* be1 = base+16; const float* bn1 = base+8;
  const float biash = be1[h] + bn1[h];

  for (int dd=0; dd<4; dd++){
    int d = d0 + dd;
    if (d >= N) break;
    size_t dq = (size_t)d*DD;
    float qv[8];
    {
      uint4 qraw = *(const uint4*)(q + dq + c8);
      const unsigned short* qh = (const unsigned short*)&qraw;
#pragma unroll
      for (int j=0;j<8;j++) qv[j] = b2f(qh[j])*0.25f;
    }
    int mn = mnid[d];
    float bias = biash + p1mn[(size_t)mn*HH + h];

    float zh = 0.f;
    float a[8];
#pragma unroll
    for (int j=0;j<8;j++) a[j] = 0.f;

    int i0 = rowptr[d], i1 = rowptr[d+1];
    int i = i0 + grp;
    for (; i + 4 < i1; i += 8){
      int s0 = esrc[i],   me0 = emeid[i];
      int s1 = esrc[i+4], me1 = emeid[i+4];
      size_t kvo0 = (size_t)s0*(2*DD), mo0 = (size_t)me0*DD;
      size_t kvo1 = (size_t)s1*(2*DD), mo1 = (size_t)me1*DD;
      uint4 kraw0 = *(const uint4*)(kv + kvo0 + c8);
      uint4 vraw0 = *(const uint4*)(kv + kvo0 + DD + c8);
      uint4 wraw0 = *(const uint4*)(w2me + mo0 + c8);
      float pm0 = b2f(p1me[(size_t)me0*HH + h]);
      uint4 kraw1 = *(const uint4*)(kv + kvo1 + c8);
      uint4 vraw1 = *(const uint4*)(kv + kvo1 + DD + c8);
      uint4 wraw1 = *(const uint4*)(w2me + mo1 + c8);
      float pm1 = b2f(p1me[(size_t)me1*HH + h]);
      const unsigned short* kh0 = (const unsigned short*)&kraw0;
      const unsigned short* wh0 = (const unsigned short*)&wraw0;
      const unsigned short* vh0 = (const unsigned short*)&vraw0;
      const unsigned short* kh1 = (const unsigned short*)&kraw1;
      const unsigned short* wh1 = (const unsigned short*)&wraw1;
      const unsigned short* vh1 = (const unsigned short*)&vraw1;
      float pA = 0.f, pB = 0.f;
#pragma unroll
      for (int j=0;j<8;j++){
        pA += qv[j]*(b2f(kh0[j])*b2f(wh0[j]));
        pB += qv[j]*(b2f(kh1[j])*b2f(wh1[j]));
      }
      pA += __shfl_xor(pA, 1, 64);
      pB += __shfl_xor(pB, 1, 64);
      float ex0 = __expf(pA + bias + pm0);
      float ex1 = __expf(pB + bias + pm1);
      zh += ex0 + ex1;
#pragma unroll
      for (int j=0;j<8;j++) a[j] += ex0*b2f(vh0[j]) + ex1*b2f(vh1[j]);
    }
    if (i < i1){
      int s = esrc[i], me = emeid[i];
      size_t kvo = (size_t)s*(2*DD), mo = (size_t)me*DD;
      uint4 kraw = *(const uint4*)(kv + kvo + c8);
      uint4 vraw = *(const uint4*)(kv + kvo + DD + c8);
      uint4 wraw = *(const uint4*)(w2me + mo + c8);
      float pm = b2f(p1me[(size_t)me*HH + h]);
      const unsigned short* kh = (const unsigned short*)&kraw;
      const unsigned short* wh = (const unsigned short*)&wraw;
      const unsigned short* vh = (const unsigned short*)&vraw;
      float p = 0.f;
#pragma unroll
      for (int j=0;j<8;j++) p += qv[j]*(b2f(kh[j])*b2f(wh[j]));
      p += __shfl_xor(p, 1, 64);
      float ex = __expf(p + bias + pm);
      zh += ex;
#pragma unroll
      for (int j=0;j<8;j++) a[j] += ex*b2f(vh[j]);
    }

    zh += __shfl_xor(zh, 16, 64); zh += __shfl_xor(zh, 32, 64);
#pragma unroll
    for (int j=0;j<8;j++){
      a[j] += __shfl_xor(a[j], 16, 64);
      a[j] += __shfl_xor(a[j], 32, 64);
    }
    if (grp == 0){
      us4 o0, o1;
      o0.x=f2b(a[0]); o0.y=f2b(a[1]); o0.z=f2b(a[2]); o0.w=f2b(a[3]);
      o1.x=f2b(a[4]); o1.y=f2b(a[5]); o1.z=f2b(a[6]); o1.w=f2b(a[7]);
      *(us4*)(aggb + dq + c8)     = o0;
      *(us4*)(aggb + dq + c8 + 4) = o1;
      if ((l16 & 1) == 0) z[(size_t)d*HH + h] = zh;
    }
  }
}

// Fused meta-learner over [meta_out (Ma rows, f32) | mef (bf16)].
__global__ __launch_bounds__(128) void learner2(
    const float* __restrict__ Xa, const unsigned short* __restrict__ Xb, int Ma,
    const void* __restrict__ u, const void* __restrict__ W2,
    const void* __restrict__ W1,
    float* __restrict__ p2a, float* __restrict__ p1a,
    unsigned short* __restrict__ w2me, unsigned short* __restrict__ p1b,
    const float* __restrict__ base, const int* __restrict__ dflag)
{
  __shared__ float sX[128];
  __shared__ float st[16];
  __shared__ float sw[16];
  const bool wf32 = (*dflag) != 0;
  const int blk = blockIdx.x, t = threadIdx.x;
  const bool isB = (blk >= Ma);
  const int m = isB ? (blk - Ma) : blk;
  if (isB) sX[t] = b2f(Xb[(size_t)m*DD + t]);
  else     sX[t] = Xa[(size_t)m*DD + t];
  __syncthreads();
  int l = t>>3, j = t&7;
  float part = 0.f;
  for (int d=j*16; d<j*16+16; d++) part += sX[d]*gld(u, l*128+d, wf32);
  part += __shfl_xor(part,1,64); part += __shfl_xor(part,2,64); part += __shfl_xor(part,4,64);
  if (j==0) st[l] = part * 0.08838834764831845f;
  __syncthreads();
  float mx=-1e30f;
  for (int i=0;i<16;i++) mx = fmaxf(mx, st[i]);
  float ssum=0.f;
  for (int i=0;i<16;i++) ssum += __expf(st[i]-mx);
  float inv = 1.f/ssum;
  if (t<16) sw[t] = __expf(st[t]-mx)*inv;
  __syncthreads();
  float a=0.f;
  for (int i=0;i<16;i++) a += sw[i]*gld(W2, i*128+t, wf32);
  if (isB) w2me[(size_t)m*DD+t] = f2b(base[152+t] + a);
  else     p2a[(size_t)m*DD+t] = a;
  if (t<8){
    float bb=0.f;
    for (int i=0;i<16;i++) bb += sw[i]*gld(W1, i*8+t, wf32);
    if (isB) p1b[(size_t)m*HH+t] = f2b(bb);
    else     p1a[(size_t)m*HH+t] = bb;
  }
}

__global__ __launch_bounds__(256) void readout(
    const int* __restrict__ tgt, const int* __restrict__ mnid,
    const unsigned short* __restrict__ featb, const float* __restrict__ p1mn,
    const float* __restrict__ base, float* __restrict__ acc,
    void* __restrict__ out, int last, float invNB, int BT,
    const int* __restrict__ dflag)
{
  int t = blockIdx.x*256 + threadIdx.x;
  if (t >= BT) return;
  int idx = tgt[t]; int mn = mnid[idx];
  float logit = 0.f;
  for (int h=0;h<8;h++){
    float tw = base[h] + p1mn[(size_t)mn*HH + h];
    float srow = 0.f;
    for (int k=0;k<16;k++) srow += b2f(featb[(size_t)idx*DD + h*16 + k]);
    logit += tw*srow;
  }
  if (!last) acc[t] = logit;
  else {
    float r = (acc[t] + logit) * invNB;
    if ((*dflag) != 0) ((float*)out)[t] = r;
    else ((__hip_bfloat16*)out)[t] = __float2bfloat16(r);
  }
}

extern "C" void kernel_launch(void* const* d_in, const int* in_sizes, int n_in,
                              void* d_out, int out_size, void* d_ws, size_t ws_size,
                              hipStream_t stream) {
  const void* emb   = d_in[0];
  const void* u     = d_in[1];
  const void* W2lat = d_in[2];
  const void* W1lat = d_in[3];
  WPtrs wptrs;
  for (int i=0;i<8;i++) wptrs.p[i] = d_in[4+i];
  const int* node_vals      = (const int*)d_in[12];
  const int* meta_node_vals = (const int*)d_in[13];
  const int* src            = (const int*)d_in[14];
  const int* dst            = (const int*)d_in[15];
  const int* meta_src       = (const int*)d_in[16];
  const int* meta_dst       = (const int*)d_in[17];
  const int* meta_node_id   = (const int*)d_in[18];
  const int* meta_edge_id   = (const int*)d_in[19];
  const int* target_idx     = (const int*)d_in[20];
  const int* static_vals    = (const int*)d_in[21];
  const int* static_src     = (const int*)d_in[22];
  const int* static_dst     = (const int*)d_in[23];

  const int N  = in_sizes[12];
  const int MN = in_sizes[13];
  const int E  = in_sizes[14];
  const int ME = in_sizes[16];
  const int BT = in_sizes[20];
  const int NSRC = in_sizes[22];
  const int NB = in_sizes[8] / (DD*DD);

  float* ws = (float*)d_ws;
  size_t off = 0;
  auto allocf = [&](size_t n){ float* p = ws + off; off += n; return p; };
  auto allocb = [&](size_t n){ unsigned short* p = (unsigned short*)(ws + off); off += (n+1)/2; return p; };
  auto alloci = [&](size_t n){ int* p = (int*)(ws + off); off += n; return p; };
  int*            dflag = (int*)ws; off += 4;
  unsigned short* feat  = allocb((size_t)N*DD);
  unsigned short* q     = allocb((size_t)N*DD);
  unsigned short* kv    = allocb((size_t)N*2*DD);
  unsigned short* aggb  = allocb((size_t)N*DD);
  float*          z     = allocf((size_t)N*HH);
  float*          meta_feat= allocf((size_t)MN*DD);
  float*          agg_m = allocf((size_t)MN*DD);
  float*          z_m   = allocf((size_t)MN*HH);
  unsigned short* q_m   = allocb((size_t)MN*DD);
  unsigned short* kf_m  = allocb((size_t)MN*DD);
  unsigned short* v_m   = allocb((size_t)MN*DD);
  float*          meta_out = allocf((size_t)MN*DD);
  unsigned short* mef   = allocb((size_t)ME*DD);
  float*          p2mn  = allocf((size_t)MN*DD);
  float*          p1mn  = allocf((size_t)MN*HH);
  unsigned short* w2me  = allocb((size_t)ME*DD);
  unsigned short* p1me  = allocb((size_t)ME*HH);
  float*          base  = allocf(280);
  float*          acc   = allocf((size_t)BT);
  unsigned short* wstage= allocb((size_t)8*NB*DD*DD);
  // big-graph CSR
  int*            rowptr= alloci((size_t)N+1);
  int*            cursor= alloci((size_t)N);
  int*            esrc  = alloci((size_t)E);
  int*            emeid = alloci((size_t)E);
  // meta-graph CSR
  int*            rowptr_m= alloci((size_t)MN+1);
  int*            cursor_m= alloci((size_t)MN);
  int*            esrc_m  = alloci((size_t)ME);
  int*            eorig_m = alloci((size_t)ME);
  // merged deg + bsum
  int*            degAll  = alloci((size_t)(N+MN));
  int*            deg     = degAll;
  int*            deg_m   = degAll + N;
  const int nb_scan   = (N + 1023)/1024;
  const int nb_scan_m = (MN + 1023)/1024;
  int*            bsum   = alloci((size_t)nb_scan);
  int*            bsum_m = alloci((size_t)nb_scan_m);
  (void)ws_size; (void)n_in; (void)out_size;

  const float* base_n2 = base + 24;

  k_detect<<<1,64,0,stream>>>((const unsigned short*)emb, dflag);
  k_static<<<1,256,0,stream>>>(emb, static_vals, static_src, static_dst,
                               u, W2lat, W1lat, base, NSRC, dflag);
  gather_rows2<<<((N+MN)*16+255)/256,256,0,stream>>>(emb, node_vals, feat, N,
      meta_node_vals, meta_feat, MN, dflag);

  // ---- merged CSR builds (once per call) ----
  const int nbE  = (E+255)/256, nbME = (ME+255)/256;
  const int nb3B = (N+255)/256, nb3M = (MN+255)/256;
  zeroi<<<(N+MN+255)/256,256,0,stream>>>(degAll, N+MN);
  k_hist2<<<nbE+nbME,256,0,stream>>>(dst, meta_dst, deg, deg_m, E, ME, nbE);
  k_scan1b<<<nb_scan+nb_scan_m,256,0,stream>>>(deg, rowptr, bsum, N, nb_scan,
      deg_m, rowptr_m, bsum_m, MN);
  k_scan2b<<<1,64,0,stream>>>(bsum, nb_scan, rowptr, N, bsum_m, nb_scan_m, rowptr_m, MN);
  k_scan3b<<<nb3B+nb3M,256,0,stream>>>(rowptr, bsum, cursor, N, nb3B,
      rowptr_m, bsum_m, cursor_m, MN);
  k_scatter2<<<nbE+nbME,256,0,stream>>>(dst, src, meta_edge_id, cursor,
      esrc, emeid, E, nbE, meta_dst, meta_src, cursor_m, esrc_m, eorig_m, ME);

  // ---- all weight blocks staged once ----
  w_repack16<<<8*NB*64,256,0,stream>>>(wptrs, wstage, NB, dflag);

  const int gm = (MN+63)/64;
  const int gN = (N+63)/64;
  const float invNB = 1.0f/(float)NB;

  for (int b=0;b<NB;b++){
    const unsigned short* wq_m = wstage + (size_t)(0*NB+b)*DD*DD;
    const unsigned short* wk_m = wstage + (size_t)(1*NB+b)*DD*DD;
    const unsigned short* wv_m = wstage + (size_t)(2*NB+b)*DD*DD;
    const unsigned short* wo_m = wstage + (size_t)(3*NB+b)*DD*DD;
    const unsigned short* wqb  = wstage + (size_t)(4*NB+b)*DD*DD;
    const unsigned short* wkb  = wstage + (size_t)(5*NB+b)*DD*DD;
    const unsigned short* wvb  = wstage + (size_t)(6*NB+b)*DD*DD;
    const unsigned short* wob  = wstage + (size_t)(7*NB+b)*DD*DD;

    // ---- meta conv (CSR, atomic-free) ----
    gemm_qkv<EPI_SCALE_CONST,false><<<gm,256,0,stream>>>(meta_feat, wq_m, wk_m, wv_m,
        q_m, kf_m, DD, v_m, DD, MN, base_n2, nullptr, nullptr);
    edge_meta_csr<<<(MN+3)/4,256,0,stream>>>(rowptr_m, esrc_m, eorig_m,
        q_m, kf_m, v_m, base, mef, z_m, agg_m, MN);
    gemm128m<EPI_RELU_RES2,true,false,false><<<gm,256,0,stream>>>(agg_m, wo_m,
        meta_out, MN, z_m, nullptr, nullptr, nullptr, nullptr, meta_feat, meta_feat);

    // ---- fused meta learners ----
    learner2<<<MN+ME,128,0,stream>>>(meta_out, mef, MN, u, W2lat, W1lat,
        p2mn, p1mn, w2me, p1me, base, dflag);

    // ---- big conv ----
    gemm_qkv<EPI_SCALE_GATHER,true><<<gN,256,0,stream>>>(feat, wqb, wkb, wvb,
        q, kv, 2*DD, kv + DD, 2*DD, N, base_n2, p2mn, meta_node_id);
    edge_fused<<<(N+15)/16,256,0,stream>>>(rowptr, esrc, emeid,
        meta_node_id, q, kv, w2me, p1me, p1mn, base, z, aggb, N);
    gemm128m<EPI_RELU_RES,true,true,true><<<gN,256,0,stream>>>(aggb, wob, feat, N,
        z, nullptr, nullptr, nullptr, feat, nullptr, nullptr);

    // ---- readout ----
    readout<<<(BT+255)/256,256,0,stream>>>(target_idx, meta_node_id, feat, p1mn,
        base, acc, d_out, (b==NB-1) ? 1 : 0, invNB, BT, dflag);
  }
}

// Round 12
// 708.229 us; speedup vs baseline: 1.2572x; 1.0918x over previous
//
#include <hip/hip_runtime.h>
#include <hip/hip_bf16.h>
#include <hip/hip_fp8.h>

#define DD   128
#define HH   8

typedef short bf16x8 __attribute__((ext_vector_type(8)));
typedef float f32x4  __attribute__((ext_vector_type(4)));

__device__ __forceinline__ float b2f(unsigned short v){
  union { unsigned int u; float f; } x; x.u = ((unsigned int)v) << 16; return x.f;
}
__device__ __forceinline__ unsigned short f2b(float f){
  __hip_bfloat16 h = __float2bfloat16(f);
  return *(unsigned short*)&h;
}
__device__ __forceinline__ unsigned char f2f8(float x){
  __hip_fp8_e4m3 h(x);
  return h.__x;
}
__device__ __forceinline__ float f82f(unsigned char b){
  __hip_fp8_e4m3 h; h.__x = b;
  return (float)h;
}
struct __align__(8) us4 { unsigned short x,y,z,w; };

__device__ __forceinline__ float gld(const void* p, size_t i, bool f32){
  if (f32) return ((const float*)p)[i];
  return b2f(((const unsigned short*)p)[i]);
}

// Detect input float dtype. flag=1 -> inputs are f32.
__global__ __launch_bounds__(64) void k_detect(const unsigned short* __restrict__ emb,
                                               int* __restrict__ flag){
  int t = threadIdx.x;
  float m = 0.f;
  for (int i=t; i<128; i+=64){
    float x = fabsf(b2f(emb[i]));
    if (x < 1e30f) m = fmaxf(m, x);
  }
#pragma unroll
  for (int s=1;s<64;s<<=1) m = fmaxf(m, __shfl_xor(m, s, 64));
  if (t==0) *flag = (m > 1e4f) ? 1 : 0;
}

// ALL weight blocks (8 tensors x NB matrices) -> bf16 TRANSPOSED staging, one launch.
struct WPtrs { const void* p[8]; };
__global__ __launch_bounds__(256) void w_repack16(
    WPtrs W, unsigned short* __restrict__ stage, int NBt,
    const int* __restrict__ dflag)
{
  const bool wf32 = (*dflag) != 0;
  int idx = blockIdx.x >> 6;
  int ti = idx / NBt, bi = idx - ti*NBt;
  size_t bo = (size_t)bi*DD*DD;
  int i = (blockIdx.x & 63)*256 + threadIdx.x;
  int k = i >> 7, n = i & 127;
  float x;
  if (wf32) x = ((const float*)W.p[ti])[bo + i];
  else      x = b2f(((const unsigned short*)W.p[ti])[bo + i]);
  stage[(size_t)idx*DD*DD + n*DD + k] = f2b(x);
}

enum { EPI_STORE=0, EPI_SCALE_CONST=1, EPI_SCALE_GATHER=2, EPI_RELU=3,
       EPI_RELU_RES=4, EPI_RELU_RES2=5 };

#define APAD 136
#define CPAD 132

// C[M,128] = epi( prologue(A)[M,128] @ B[128,128] ), B bf16 TRANSPOSED ([n][k]).
template<int EPI, bool NORM, bool INB, bool OUTB>
__global__ __launch_bounds__(256) void gemm128m(
    const void* __restrict__ Av, const unsigned short* __restrict__ Bt,
    void* __restrict__ Cv, int M,
    const float* __restrict__ z, const float* __restrict__ svec,
    const float* __restrict__ P2, const int* __restrict__ gidx,
    const unsigned short* __restrict__ Rb,
    const float* __restrict__ Rf, float* __restrict__ C2)
{
  __shared__ unsigned short Asb[64*APAD];
  __shared__ unsigned short Btb[128*APAD];
  const int tid = threadIdx.x;
  const int wave = tid >> 6, lane = tid & 63;
  const int row0 = blockIdx.x * 64;

  {
    int r = tid >> 2, cb = (tid & 3) * 32;
    int gr = row0 + r;
    if (INB){
      const unsigned short* Ab = (const unsigned short*)Av;
#pragma unroll
      for (int j=0;j<4;j++){
        int c = cb + j*8;
        uint4 raw = make_uint4(0,0,0,0);
        if (gr < M) raw = *(const uint4*)(Ab + (size_t)gr*DD + c);
        if (NORM){
          float s = 0.f;
          if (gr < M) s = 1.0f/(z[(size_t)gr*HH + (c>>4)] + 1e-9f);
          const unsigned short* hw = (const unsigned short*)&raw;
          us4 o0, o1;
          o0.x=f2b(b2f(hw[0])*s); o0.y=f2b(b2f(hw[1])*s);
          o0.z=f2b(b2f(hw[2])*s); o0.w=f2b(b2f(hw[3])*s);
          o1.x=f2b(b2f(hw[4])*s); o1.y=f2b(b2f(hw[5])*s);
          o1.z=f2b(b2f(hw[6])*s); o1.w=f2b(b2f(hw[7])*s);
          *(us4*)&Asb[r*APAD + c] = o0; *(us4*)&Asb[r*APAD + c + 4] = o1;
        } else {
          *(uint4*)&Asb[r*APAD + c] = raw;
        }
      }
    } else {
      const float* Af = (const float*)Av;
#pragma unroll
      for (int j=0;j<8;j++){
        int c = cb + j*4;
        float4 val = make_float4(0.f,0.f,0.f,0.f);
        if (gr < M){
          val = *(const float4*)(Af + (size_t)gr*DD + c);
          if (NORM){
            float s = 1.0f / (z[(size_t)gr*HH + (c>>4)] + 1e-9f);
            val.x*=s; val.y*=s; val.z*=s; val.w*=s;
          }
        }
        us4 o; o.x=f2b(val.x); o.y=f2b(val.y); o.z=f2b(val.z); o.w=f2b(val.w);
        *(us4*)&Asb[r*APAD + c] = o;
      }
    }
  }
  {
    int n = tid >> 1, k0s = (tid & 1) * 64;
#pragma unroll
    for (int j=0;j<8;j++){
      uint4 raw = *(const uint4*)(Bt + (size_t)n*DD + k0s + j*8);
      *(uint4*)&Btb[n*APAD + k0s + j*8] = raw;
    }
  }
  __syncthreads();

  f32x4 acc[8];
#pragma unroll
  for (int t=0;t<8;t++) acc[t] = (f32x4){0.f,0.f,0.f,0.f};
  const int am = (lane & 15), kq = (lane >> 4) * 8;
#pragma unroll
  for (int k0=0;k0<128;k0+=32){
    bf16x8 a = *(bf16x8*)&Asb[(wave*16 + am)*APAD + k0 + kq];
#pragma unroll
    for (int t=0;t<8;t++){
      bf16x8 b = *(bf16x8*)&Btb[(t*16 + am)*APAD + k0 + kq];
      acc[t] = __builtin_amdgcn_mfma_f32_16x16x32_bf16(a, b, acc[t], 0,0,0);
    }
  }
  __syncthreads();
  float* Cls = (float*)Btb;
  {
    int rr = wave*16 + (lane>>4)*4;
    int cc = lane & 15;
#pragma unroll
    for (int t=0;t<8;t++)
#pragma unroll
      for (int r=0;r<4;r++)
        Cls[(rr + r)*CPAD + t*16 + cc] = acc[t][r];
  }
  __syncthreads();

  {
    int r = tid >> 2, cb = (tid & 3) * 32;
    int gr = row0 + r;
    if (gr < M){
#pragma unroll
      for (int j=0;j<8;j++){
        int c = cb + j*4;
        float4 o = *(float4*)&Cls[r*CPAD + c];
        if (EPI == EPI_SCALE_CONST){
          o.x*=svec[c+0]; o.y*=svec[c+1]; o.z*=svec[c+2]; o.w*=svec[c+3];
        } else if (EPI == EPI_SCALE_GATHER){
          int g = gidx[gr];
          const float* p = P2 + (size_t)g*DD + c;
          o.x*=(svec[c+0]+p[0]); o.y*=(svec[c+1]+p[1]);
          o.z*=(svec[c+2]+p[2]); o.w*=(svec[c+3]+p[3]);
        } else if (EPI == EPI_RELU){
          o.x=fmaxf(o.x,0.f); o.y=fmaxf(o.y,0.f); o.z=fmaxf(o.z,0.f); o.w=fmaxf(o.w,0.f);
        } else if (EPI == EPI_RELU_RES){
          us4 rb = *(const us4*)(Rb + (size_t)gr*DD + c);
          o.x=fmaxf(o.x,0.f)+b2f(rb.x); o.y=fmaxf(o.y,0.f)+b2f(rb.y);
          o.z=fmaxf(o.z,0.f)+b2f(rb.z); o.w=fmaxf(o.w,0.f)+b2f(rb.w);
        } else if (EPI == EPI_RELU_RES2){
          o.x=fmaxf(o.x,0.f); o.y=fmaxf(o.y,0.f); o.z=fmaxf(o.z,0.f); o.w=fmaxf(o.w,0.f);
          float4 rf = *(const float4*)(Rf + (size_t)gr*DD + c);
          *(float4*)(C2 + (size_t)gr*DD + c) =
              make_float4(o.x+rf.x, o.y+rf.y, o.z+rf.z, o.w+rf.w);
        }
        if (OUTB){
          us4 ob; ob.x=f2b(o.x); ob.y=f2b(o.y); ob.z=f2b(o.z); ob.w=f2b(o.w);
          *(us4*)((unsigned short*)Cv + (size_t)gr*DD + c) = ob;
        } else {
          *(float4*)((float*)Cv + (size_t)gr*DD + c) = o;
        }
      }
    }
  }
}

// Fused Q/K/V gemm. FP8KV: phases 1/2 write fp8 (x8 scale) into 256B/row kv buffer
// (Ck = kv8 base, Cvo = kv8+128); phase 0 (q) writes bf16.
template<int EPIQ, bool INB, bool FP8KV>
__global__ __launch_bounds__(256) void gemm_qkv(
    const void* __restrict__ Av,
    const unsigned short* __restrict__ Btq, const unsigned short* __restrict__ Btk,
    const unsigned short* __restrict__ Btv,
    void* __restrict__ Cq, void* __restrict__ Ck, int stK,
    void* __restrict__ Cvo, int stV, int M,
    const float* __restrict__ svec, const float* __restrict__ P2,
    const int* __restrict__ gidx)
{
  __shared__ unsigned short Asb[64*APAD];
  __shared__ unsigned short Btb[128*APAD];
  const int tid = threadIdx.x;
  const int wave = tid >> 6, lane = tid & 63;
  const int row0 = blockIdx.x * 64;

  {
    int r = tid >> 2, cb = (tid & 3) * 32;
    int gr = row0 + r;
    if (INB){
      const unsigned short* Ab = (const unsigned short*)Av;
#pragma unroll
      for (int j=0;j<4;j++){
        int c = cb + j*8;
        uint4 raw = make_uint4(0,0,0,0);
        if (gr < M) raw = *(const uint4*)(Ab + (size_t)gr*DD + c);
        *(uint4*)&Asb[r*APAD + c] = raw;
      }
    } else {
      const float* Af = (const float*)Av;
#pragma unroll
      for (int j=0;j<8;j++){
        int c = cb + j*4;
        float4 val = make_float4(0.f,0.f,0.f,0.f);
        if (gr < M) val = *(const float4*)(Af + (size_t)gr*DD + c);
        us4 o; o.x=f2b(val.x); o.y=f2b(val.y); o.z=f2b(val.z); o.w=f2b(val.w);
        *(us4*)&Asb[r*APAD + c] = o;
      }
    }
  }

  const unsigned short* Bts[3] = {Btq, Btk, Btv};
  void* Cs[3] = {Cq, Ck, Cvo};
  const int sts[3] = {DD, stK, stV};
  const int am = (lane & 15), kq = (lane >> 4) * 8;

  for (int ph=0; ph<3; ph++){
    {
      int n = tid >> 1, k0s = (tid & 1) * 64;
      const unsigned short* Bt = Bts[ph];
#pragma unroll
      for (int j=0;j<8;j++){
        uint4 raw = *(const uint4*)(Bt + (size_t)n*DD + k0s + j*8);
        *(uint4*)&Btb[n*APAD + k0s + j*8] = raw;
      }
    }
    __syncthreads();
    f32x4 acc[8];
#pragma unroll
    for (int t=0;t<8;t++) acc[t] = (f32x4){0.f,0.f,0.f,0.f};
#pragma unroll
    for (int k0=0;k0<128;k0+=32){
      bf16x8 a = *(bf16x8*)&Asb[(wave*16 + am)*APAD + k0 + kq];
#pragma unroll
      for (int t=0;t<8;t++){
        bf16x8 b = *(bf16x8*)&Btb[(t*16 + am)*APAD + k0 + kq];
        acc[t] = __builtin_amdgcn_mfma_f32_16x16x32_bf16(a, b, acc[t], 0,0,0);
      }
    }
    __syncthreads();
    float* Cls = (float*)Btb;
    {
      int rr = wave*16 + (lane>>4)*4;
      int cc = lane & 15;
#pragma unroll
      for (int t=0;t<8;t++)
#pragma unroll
        for (int r=0;r<4;r++)
          Cls[(rr + r)*CPAD + t*16 + cc] = acc[t][r];
    }
    __syncthreads();
    {
      int r = tid >> 2, cb = (tid & 3) * 32;
      int gr = row0 + r;
      if (gr < M){
#pragma unroll
        for (int j=0;j<8;j++){
          int c = cb + j*4;
          float4 o = *(float4*)&Cls[r*CPAD + c];
          if (ph == 0){
            if (EPIQ == EPI_SCALE_GATHER){
              int g = gidx[gr];
              const float* p = P2 + (size_t)g*DD + c;
              o.x*=(svec[c+0]+p[0]); o.y*=(svec[c+1]+p[1]);
              o.z*=(svec[c+2]+p[2]); o.w*=(svec[c+3]+p[3]);
            } else {
              o.x*=svec[c+0]; o.y*=svec[c+1]; o.z*=svec[c+2]; o.w*=svec[c+3];
            }
          }
          if (FP8KV && ph > 0){
            unsigned char* Cb = (unsigned char*)Cs[ph];
            uchar4 ob;
            ob.x=f2f8(o.x*8.f); ob.y=f2f8(o.y*8.f);
            ob.z=f2f8(o.z*8.f); ob.w=f2f8(o.w*8.f);
            *(uchar4*)(Cb + (size_t)gr*256 + c) = ob;
          } else {
            us4 ob; ob.x=f2b(o.x); ob.y=f2b(o.y); ob.z=f2b(o.z); ob.w=f2b(o.w);
            *(us4*)((unsigned short*)Cs[ph] + (size_t)gr*sts[ph] + c) = ob;
          }
        }
      }
    }
    __syncthreads();
  }
}

// Static param-name graph -> base params.
__global__ __launch_bounds__(256) void k_static(
    const void* __restrict__ emb, const int* __restrict__ svals,
    const int* __restrict__ ssrc, const int* __restrict__ sdst,
    const void* __restrict__ u, const void* __restrict__ W2,
    const void* __restrict__ W1, float* __restrict__ base, int nsrc,
    const int* __restrict__ dflag)
{
  __shared__ float sagg[15][128];
  __shared__ float ssc[15][16];
  __shared__ float sww[15][16];
  const bool wf32 = (*dflag) != 0;
  const int t = threadIdx.x;
  for (int i=t;i<15*128;i+=256) ((float*)sagg)[i]=0.f;
  __syncthreads();
  if (t < 128){
    for (int i=0;i<nsrc;i++){
      int row = sdst[i]; int vr = svals[ssrc[i]];
      sagg[row][t] += gld(emb, (size_t)vr*DD + t, wf32);
    }
  }
  __syncthreads();
  if (t < 240){
    int n = t>>4, l = t&15;
    float a=0.f;
    for (int d=0;d<128;d++) a += sagg[n][d]*gld(u, l*128+d, wf32);
    ssc[n][l] = a * 0.08838834764831845f;
  }
  __syncthreads();
  if (t < 15){
    float mx=-1e30f;
    for (int l=0;l<16;l++) mx = fmaxf(mx, ssc[t][l]);
    float s=0.f;
    for (int l=0;l<16;l++){ float e=__expf(ssc[t][l]-mx); sww[t][l]=e; s+=e; }
    float inv = 1.f/s;
    for (int l=0;l<16;l++) sww[t][l]*=inv;
  }
  __syncthreads();
  if (t < 8){
    float a=0.f,b=0.f,c=0.f;
    for (int l=0;l<16;l++){
      float wv = gld(W1, l*8+t, wf32);
      a += sww[0][l]*wv; b += sww[3][l]*wv; c += sww[9][l]*wv;
    }
    base[t]=a; base[8+t]=b; base[16+t]=c;
  }
  if (t < 128){
    float a=0.f,b=0.f;
    for (int l=0;l<16;l++){
      float wv = gld(W2, l*128+t, wf32);
      a += sww[6][l]*wv; b += sww[12][l]*wv;
    }
    base[24+t]=a; base[152+t]=b;
  }
}

// Merged gather: big graph rows -> bf16 feat; meta rows -> f32 meta_feat.
__global__ __launch_bounds__(256) void gather_rows2(
    const void* __restrict__ emb,
    const int* __restrict__ valsB, unsigned short* __restrict__ featB, int nB,
    const int* __restrict__ valsM, float* __restrict__ featM, int nM,
    const int* __restrict__ dflag)
{
  const bool wf32 = (*dflag) != 0;
  int i = blockIdx.x*256 + threadIdx.x;
  bool big = (i < nB*16);
  int i2 = big ? i : (i - nB*16);
  if (!big && i2 >= nM*16) return;
  int r = i2>>4, c = (i2&15)*8;
  int vr = big ? valsB[r] : valsM[r];
  float vb[8];
  if (wf32){
    float4 f0 = *(const float4*)((const float*)emb + (size_t)vr*DD + c);
    float4 f1 = *(const float4*)((const float*)emb + (size_t)vr*DD + c + 4);
    vb[0]=f0.x; vb[1]=f0.y; vb[2]=f0.z; vb[3]=f0.w;
    vb[4]=f1.x; vb[5]=f1.y; vb[6]=f1.z; vb[7]=f1.w;
  } else {
    uint4 raw = *(const uint4*)((const unsigned short*)emb + (size_t)vr*DD + c);
    const unsigned short* hw = (const unsigned short*)&raw;
#pragma unroll
    for (int j=0;j<8;j++) vb[j] = b2f(hw[j]);
  }
  if (big){
    unsigned short* d = featB + (size_t)r*DD + c;
    us4 o0, o1;
    o0.x=f2b(vb[0]); o0.y=f2b(vb[1]); o0.z=f2b(vb[2]); o0.w=f2b(vb[3]);
    o1.x=f2b(vb[4]); o1.y=f2b(vb[5]); o1.z=f2b(vb[6]); o1.w=f2b(vb[7]);
    *(us4*)d = o0; *(us4*)(d+4) = o1;
  } else {
    float* d = featM + (size_t)r*DD + c;
    *(float4*)d     = make_float4(vb[0],vb[1],vb[2],vb[3]);
    *(float4*)(d+4) = make_float4(vb[4],vb[5],vb[6],vb[7]);
  }
}

__global__ __launch_bounds__(256) void zeroi(int* __restrict__ p, int n){
  int i = blockIdx.x*256 + threadIdx.x;
  if (i < n) p[i] = 0;
}

// ---------------- merged CSR build (big + meta graphs) ----------------
__global__ __launch_bounds__(256) void k_hist2(
    const int* __restrict__ dstB, const int* __restrict__ dstM,
    int* __restrict__ degB, int* __restrict__ degM, int E, int ME, int nbE){
  int b = blockIdx.x, t = threadIdx.x;
  if (b < nbE){ int i = b*256+t; if (i < E) atomicAdd(&degB[dstB[i]], 1); }
  else { int i = (b-nbE)*256+t; if (i < ME) atomicAdd(&degM[dstM[i]], 1); }
}

__global__ __launch_bounds__(256) void k_scan1b(
    const int* __restrict__ degB, int* __restrict__ rpB, int* __restrict__ bsB,
    int nB, int nbB,
    const int* __restrict__ degM, int* __restrict__ rpM, int* __restrict__ bsM,
    int nM){
  __shared__ int ls[256];
  int blk = blockIdx.x, t = threadIdx.x;
  const int* deg; int* rowptr; int* bsum; int n; int b;
  if (blk < nbB){ deg=degB; rowptr=rpB; bsum=bsB; n=nB; b=blk; }
  else          { deg=degM; rowptr=rpM; bsum=bsM; n=nM; b=blk-nbB; }
  int base = b*1024 + t*4;
  int v0 = (base+0<n)?deg[base+0]:0;
  int v1 = (base+1<n)?deg[base+1]:0;
  int v2 = (base+2<n)?deg[base+2]:0;
  int v3 = (base+3<n)?deg[base+3]:0;
  int tsum = v0+v1+v2+v3;
  ls[t] = tsum; __syncthreads();
  for (int o=1;o<256;o<<=1){
    int x = (t>=o) ? ls[t-o] : 0;
    __syncthreads();
    ls[t] += x;
    __syncthreads();
  }
  int excl = ls[t]-tsum;
  if (t==255) bsum[b] = ls[255];
  if (base+0<n) rowptr[base+0]=excl;
  if (base+1<n) rowptr[base+1]=excl+v0;
  if (base+2<n) rowptr[base+2]=excl+v0+v1;
  if (base+3<n) rowptr[base+3]=excl+v0+v1+v2;
}

__global__ __launch_bounds__(64) void k_scan2b(
    int* __restrict__ bsB, int nbB, int* __restrict__ rpB, int nB,
    int* __restrict__ bsM, int nbM, int* __restrict__ rpM, int nM){
  int t = threadIdx.x;
  if (t == 0){
    int run = 0;
    for (int b=0;b<nbB;b++){ int x = bsB[b]; bsB[b] = run; run += x; }
    rpB[nB] = run;
  } else if (t == 1){
    int run = 0;
    for (int b=0;b<nbM;b++){ int x = bsM[b]; bsM[b] = run; run += x; }
    rpM[nM] = run;
  }
}

__global__ __launch_bounds__(256) void k_scan3b(
    int* __restrict__ rpB, const int* __restrict__ bsB, int* __restrict__ curB,
    int nB, int nb3B,
    int* __restrict__ rpM, const int* __restrict__ bsM, int* __restrict__ curM,
    int nM){
  int blk = blockIdx.x, t = threadIdx.x;
  if (blk < nb3B){
    int i = blk*256 + t;
    if (i < nB){ int r = rpB[i] + bsB[i>>10]; rpB[i] = r; curB[i] = r; }
  } else {
    int i = (blk-nb3B)*256 + t;
    if (i < nM){ int r = rpM[i] + bsM[i>>10]; rpM[i] = r; curM[i] = r; }
  }
}

__global__ __launch_bounds__(256) void k_scatter2(
    const int* __restrict__ dstB, const int* __restrict__ srcB,
    const int* __restrict__ auxB, int* __restrict__ curB,
    int* __restrict__ esrcB, int* __restrict__ eauxB, int E, int nbE,
    const int* __restrict__ dstM, const int* __restrict__ srcM,
    int* __restrict__ curM, int* __restrict__ esrcM, int* __restrict__ eauxM,
    int ME){
  int blk = blockIdx.x, t = threadIdx.x;
  if (blk < nbE){
    int e = blk*256 + t;
    if (e < E){
      int p = atomicAdd(&curB[dstB[e]], 1);
      esrcB[p] = srcB[e];
      eauxB[p] = auxB[e];
    }
  } else {
    int e = (blk-nbE)*256 + t;
    if (e < ME){
      int p = atomicAdd(&curM[dstM[e]], 1);
      esrcM[p] = srcM[e];
      eauxM[p] = e;
    }
  }
}

// ---------------- meta-graph edges: CSR, atomic-free, writes mef ----------------
__global__ __launch_bounds__(256) void edge_meta_csr(
    const int* __restrict__ rowptr, const int* __restrict__ esrc,
    const int* __restrict__ eorig,
    const unsigned short* __restrict__ qm, const unsigned short* __restrict__ kfm,
    const unsigned short* __restrict__ vm,
    const float* __restrict__ base, unsigned short* __restrict__ mef,
    float* __restrict__ z, float* __restrict__ agg, int NM)
{
  int d = blockIdx.x*4 + (threadIdx.x>>6);
  if (d >= NM) return;
  int lane = threadIdx.x & 63;
  const float* be2 = base+152; const float* be1 = base+16; const float* bn1 = base+8;
  size_t dq = (size_t)d*DD;
  float q0 = b2f(qm[dq+lane]), q1 = b2f(qm[dq+64+lane]);
  float w0 = be2[lane], w1 = be2[64+lane];
  int h0 = lane>>4, h1 = h0+4;
  float bias0 = be1[h0] + bn1[h0];
  float bias1 = be1[h1] + bn1[h1];
  float z0=0.f, z1=0.f, a0=0.f, a1=0.f;
  int i0 = rowptr[d], i1 = rowptr[d+1];
  for (int i=i0; i<i1; i++){
    int s = esrc[i], e = eorig[i];
    size_t so=(size_t)s*DD, eo=(size_t)e*DD;
    float ke0 = b2f(kfm[so+lane])    * w0;
    float ke1 = b2f(kfm[so+64+lane]) * w1;
    mef[eo+lane]=f2b(ke0); mef[eo+64+lane]=f2b(ke1);
    float p0 = q0*ke0, p1 = q1*ke1;
#pragma unroll
    for (int m=1;m<16;m<<=1){ p0 += __shfl_xor(p0,m,64); p1 += __shfl_xor(p1,m,64); }
    float e0 = __expf(p0*0.25f + bias0);
    float e1 = __expf(p1*0.25f + bias1);
    z0 += e0; z1 += e1;
    a0 += e0*b2f(vm[so+lane]);
    a1 += e1*b2f(vm[so+64+lane]);
  }
  if ((lane&15)==0){ z[(size_t)d*HH+h0] = z0; z[(size_t)d*HH+h1] = z1; }
  agg[dq+lane]    = a0;
  agg[dq+64+lane] = a1;
}

// ---------------- big-graph: fused scores+agg, fp8 kv (256B/row) ----------------
__global__ __launch_bounds__(256) void edge_fused(
    const int* __restrict__ rowptr,
    const int* __restrict__ esrc, const int* __restrict__ emeid,
    const int* __restrict__ mnid,
    const unsigned short* __restrict__ q, const unsigned char* __restrict__ kv8,
    const unsigned short* __restrict__ w2me, const unsigned short* __restrict__ p1me,
    const float* __restrict__ p1mn, const float* __restrict__ base,
    float* __restrict__ z, unsigned short* __restrict__ aggb, int N)
{
  int wv = blockIdx.x*4 + (threadIdx.x>>6);
  int d0 = wv*4;
  if (d0 >= N) return;
  int lane = threadIdx.x & 63;
  int grp = lane >> 4, l16 = lane & 15;
  int c8 = l16 * 8;
  int h = l16 >> 1;
  const float* be1 = base+16; const float* bn1 = base+8;
  const float biash = be1[h] + bn1[h];

  for (int dd=0; dd<4; dd++){
    int d = d0 + dd;
    if (d >= N) break;
    size_t dq = (size_t)d*DD;
    float qv[8];
    {
      uint4 qraw = *(const uint4*)(q + dq + c8);
      const unsigned short* qh = (const unsigned short*)&qraw;
#pragma unroll
      for (int j=0;j<8;j++) qv[j] = b2f(qh[j])*0.03125f;  // 0.25 * 1/8 (k fp8 scale)
    }
    int mn = mnid[d];
    float bias = biash + p1mn[(size_t)mn*HH + h];

    float zh = 0.f;
    float a[8];
#pragma unroll
    for (int j=0;j<8;j++) a[j] = 0.f;

    int i0 = rowptr[d], i1 = rowptr[d+1];
    int i = i0 + grp;
    for (; i + 4 < i1; i += 8){
      int s0 = esrc[i],   me0 = emeid[i];
      int s1 = esrc[i+4], me1 = emeid[i+4];
      size_t kvo0 = (size_t)s0*256, mo0 = (size_t)me0*DD;
      size_t kvo1 = (size_t)s1*256, mo1 = (size_t)me1*DD;
      uint2 kraw0 = *(const uint2*)(kv8 + kvo0 + c8);
      uint2 vraw0 = *(const uint2*)(kv8 + kvo0 + 128 + c8);
      uint4 wraw0 = *(const uint4*)(w2me + mo0 + c8);
      float pm0 = b2f(p1me[(size_t)me0*HH + h]);
      uint2 kraw1 = *(const uint2*)(kv8 + kvo1 + c8);
      uint2 vraw1 = *(const uint2*)(kv8 + kvo1 + 128 + c8);
      uint4 wraw1 = *(const uint4*)(w2me + mo1 + c8);
      float pm1 = b2f(p1me[(size_t)me1*HH + h]);
      const unsigned char* kh0 = (const unsigned char*)&kraw0;
      const unsigned char* vh0 = (const unsigned char*)&vraw0;
      const unsigned short* wh0 = (const unsigned short*)&wraw0;
      const unsigned char* kh1 = (const unsigned char*)&kraw1;
      const unsigned char* vh1 = (const unsigned char*)&vraw1;
      const unsigned short* wh1 = (const unsigned short*)&wraw1;
      float pA = 0.f, pB = 0.f;
#pragma unroll
      for (int j=0;j<8;j++){
        pA += qv[j]*(f82f(kh0[j])*b2f(wh0[j]));
        pB += qv[j]*(f82f(kh1[j])*b2f(wh1[j]));
      }
      pA += __shfl_xor(pA, 1, 64);
      pB += __shfl_xor(pB, 1, 64);
      float ex0 = __expf(pA + bias + pm0);
      float ex1 = __expf(pB + bias + pm1);
      zh += ex0 + ex1;
      float ev0 = ex0*0.125f, ev1 = ex1*0.125f;   // v fp8 scale
#pragma unroll
      for (int j=0;j<8;j++) a[j] += ev0*f82f(vh0[j]) + ev1*f82f(vh1[j]);
    }
    if (i < i1){
      int s = esrc[i], me = emeid[i];
      size_t kvo = (size_t)s*256, mo = (size_t)me*DD;
      uint2 kraw = *(const uint2*)(kv8 + kvo + c8);
      uint2 vraw = *(const uint2*)(kv8 + kvo + 128 + c8);
      uint4 wraw = *(const uint4*)(w2me + mo + c8);
      float pm = b2f(p1me[(size_t)me*HH + h]);
      const unsigned char* kh = (const unsigned char*)&kraw;
      const unsigned char* vh = (const unsigned char*)&vraw;
      const unsigned short* wh = (const unsigned short*)&wraw;
      float p = 0.f;
#pragma unroll
      for (int j=0;j<8;j++) p += qv[j]*(f82f(kh[j])*b2f(wh[j]));
      p += __shfl_xor(p, 1, 64);
      float ex = __expf(p + bias + pm);
      zh += ex;
      float ev = ex*0.125f;
#pragma unroll
      for (int j=0;j<8;j++) a[j] += ev*f82f(vh[j]);
    }

    zh += __shfl_xor(zh, 16, 64); zh += __shfl_xor(zh, 32, 64);
#pragma unroll
    for (int j=0;j<8;j++){
      a[j] += __shfl_xor(a[j], 16, 64);
      a[j] += __shfl_xor(a[j], 32, 64);
    }
    if (grp == 0){
      us4 o0, o1;
      o0.x=f2b(a[0]); o0.y=f2b(a[1]); o0.z=f2b(a[2]); o0.w=f2b(a[3]);
      o1.x=f2b(a[4]); o1.y=f2b(a[5]); o1.z=f2b(a[6]); o1.w=f2b(a[7]);
      *(us4*)(aggb + dq + c8)     = o0;
      *(us4*)(aggb + dq + c8 + 4) = o1;
      if ((l16 & 1) == 0) z[(size_t)d*HH + h] = zh;
    }
  }
}

// Fused meta-learner over [meta_out (Ma rows, f32) | mef (bf16)].
__global__ __launch_bounds__(128) void learner2(
    const float* __restrict__ Xa, const unsigned short* __restrict__ Xb, int Ma,
    const void* __restrict__ u, const void* __restrict__ W2,
    const void* __restrict__ W1,
    float* __restrict__ p2a, float* __restrict__ p1a,
    unsigned short* __restrict__ w2me, unsigned short* __restrict__ p1b,
    const float* __restrict__ base, const int* __restrict__ dflag)
{
  __shared__ float sX[128];
  __shared__ float st[16];
  __shared__ float sw[16];
  const bool wf32 = (*dflag) != 0;
  const int blk = blockIdx.x, t = threadIdx.x;
  const bool isB = (blk >= Ma);
  const int m = isB ? (blk - Ma) : blk;
  if (isB) sX[t] = b2f(Xb[(size_t)m*DD + t]);
  else     sX[t] = Xa[(size_t)m*DD + t];
  __syncthreads();
  int l = t>>3, j = t&7;
  float part = 0.f;
  for (int d=j*16; d<j*16+16; d++) part += sX[d]*gld(u, l*128+d, wf32);
  part += __shfl_xor(part,1,64); part += __shfl_xor(part,2,64); part += __shfl_xor(part,4,64);
  if (j==0) st[l] = part * 0.08838834764831845f;
  __syncthreads();
  float mx=-1e30f;
  for (int i=0;i<16;i++) mx = fmaxf(mx, st[i]);
  float ssum=0.f;
  for (int i=0;i<16;i++) ssum += __expf(st[i]-mx);
  float inv = 1.f/ssum;
  if (t<16) sw[t] = __expf(st[t]-mx)*inv;
  __syncthreads();
  float a=0.f;
  for (int i=0;i<16;i++) a += sw[i]*gld(W2, i*128+t, wf32);
  if (isB) w2me[(size_t)m*DD+t] = f2b(base[152+t] + a);
  else     p2a[(size_t)m*DD+t] = a;
  if (t<8){
    float bb=0.f;
    for (int i=0;i<16;i++) bb += sw[i]*gld(W1, i*8+t, wf32);
    if (isB) p1b[(size_t)m*HH+t] = f2b(bb);
    else     p1a[(size_t)m*HH+t] = bb;
  }
}

// One 16-lane group per target; vectorized feat row read + shuffle reduce.
__global__ __launch_bounds__(256) void readout(
    const int* __restrict__ tgt, const int* __restrict__ mnid,
    const unsigned short* __restrict__ featb, const float* __restrict__ p1mn,
    const float* __restrict__ base, float* __restrict__ acc,
    void* __restrict__ out, int last, float invNB, int BT,
    const int* __restrict__ dflag)
{
  int t = blockIdx.x*256 + threadIdx.x;
  int ti = t >> 4, l16 = t & 15;
  if (ti >= BT) return;
  int idx = tgt[ti]; int mn = mnid[idx];
  int h = l16 >> 1;
  float tw = base[h] + p1mn[(size_t)mn*HH + h];
  uint4 raw = *(const uint4*)(featb + (size_t)idx*DD + l16*8);
  const unsigned short* hw = (const unsigned short*)&raw;
  float s = 0.f;
#pragma unroll
  for (int j=0;j<8;j++) s += b2f(hw[j]);
  float part = tw * s;
  part += __shfl_xor(part, 1, 64);
  part += __shfl_xor(part, 2, 64);
  part += __shfl_xor(part, 4, 64);
  part += __shfl_xor(part, 8, 64);
  if (l16 == 0){
    if (!last) acc[ti] = part;
    else {
      float r = (acc[ti] + part) * invNB;
      if ((*dflag) != 0) ((float*)out)[ti] = r;
      else ((__hip_bfloat16*)out)[ti] = __float2bfloat16(r);
    }
  }
}

extern "C" void kernel_launch(void* const* d_in, const int* in_sizes, int n_in,
                              void* d_out, int out_size, void* d_ws, size_t ws_size,
                              hipStream_t stream) {
  const void* emb   = d_in[0];
  const void* u     = d_in[1];
  const void* W2lat = d_in[2];
  const void* W1lat = d_in[3];
  WPtrs wptrs;
  for (int i=0;i<8;i++) wptrs.p[i] = d_in[4+i];
  const int* node_vals      = (const int*)d_in[12];
  const int* meta_node_vals = (const int*)d_in[13];
  const int* src            = (const int*)d_in[14];
  const int* dst            = (const int*)d_in[15];
  const int* meta_src       = (const int*)d_in[16];
  const int* meta_dst       = (const int*)d_in[17];
  const int* meta_node_id   = (const int*)d_in[18];
  const int* meta_edge_id   = (const int*)d_in[19];
  const int* target_idx     = (const int*)d_in[20];
  const int* static_vals    = (const int*)d_in[21];
  const int* static_src     = (const int*)d_in[22];
  const int* static_dst     = (const int*)d_in[23];

  const int N  = in_sizes[12];
  const int MN = in_sizes[13];
  const int E  = in_sizes[14];
  const int ME = in_sizes[16];
  const int BT = in_sizes[20];
  const int NSRC = in_sizes[22];
  const int NB = in_sizes[8] / (DD*DD);

  float* ws = (float*)d_ws;
  size_t off = 0;
  auto allocf = [&](size_t n){ float* p = ws + off; off += n; return p; };
  auto allocb = [&](size_t n){ unsigned short* p = (unsigned short*)(ws + off); off += (n+1)/2; return p; };
  auto alloci = [&](size_t n){ int* p = (int*)(ws + off); off += n; return p; };
  int*            dflag = (int*)ws; off += 4;
  unsigned short* feat  = allocb((size_t)N*DD);
  unsigned short* q     = allocb((size_t)N*DD);
  unsigned char*  kv8   = (unsigned char*)allocf((size_t)N*64);  // N x 256B fp8 rows
  unsigned short* aggb  = allocb((size_t)N*DD);
  float*          z     = allocf((size_t)N*HH);
  float*          meta_feat= allocf((size_t)MN*DD);
  float*          agg_m = allocf((size_t)MN*DD);
  float*          z_m   = allocf((size_t)MN*HH);
  unsigned short* q_m   = allocb((size_t)MN*DD);
  unsigned short* kf_m  = allocb((size_t)MN*DD);
  unsigned short* v_m   = allocb((size_t)MN*DD);
  float*          meta_out = allocf((size_t)MN*DD);
  unsigned short* mef   = allocb((size_t)ME*DD);
  float*          p2mn  = allocf((size_t)MN*DD);
  float*          p1mn  = allocf((size_t)MN*HH);
  unsigned short* w2me  = allocb((size_t)ME*DD);
  unsigned short* p1me  = allocb((size_t)ME*HH);
  float*          base  = allocf(280);
  float*          acc   = allocf((size_t)BT);
  unsigned short* wstage= allocb((size_t)8*NB*DD*DD);
  int*            rowptr= alloci((size_t)N+1);
  int*            cursor= alloci((size_t)N);
  int*            esrc  = alloci((size_t)E);
  int*            emeid = alloci((size_t)E);
  int*            rowptr_m= alloci((size_t)MN+1);
  int*            cursor_m= alloci((size_t)MN);
  int*            esrc_m  = alloci((size_t)ME);
  int*            eorig_m = alloci((size_t)ME);
  int*            degAll  = alloci((size_t)(N+MN));
  int*            deg     = degAll;
  int*            deg_m   = degAll + N;
  const int nb_scan   = (N + 1023)/1024;
  const int nb_scan_m = (MN + 1023)/1024;
  int*            bsum   = alloci((size_t)nb_scan);
  int*            bsum_m = alloci((size_t)nb_scan_m);
  (void)ws_size; (void)n_in; (void)out_size;

  const float* base_n2 = base + 24;

  k_detect<<<1,64,0,stream>>>((const unsigned short*)emb, dflag);
  k_static<<<1,256,0,stream>>>(emb, static_vals, static_src, static_dst,
                               u, W2lat, W1lat, base, NSRC, dflag);
  gather_rows2<<<((N+MN)*16+255)/256,256,0,stream>>>(emb, node_vals, feat, N,
      meta_node_vals, meta_feat, MN, dflag);

  const int nbE  = (E+255)/256, nbME = (ME+255)/256;
  const int nb3B = (N+255)/256, nb3M = (MN+255)/256;
  zeroi<<<(N+MN+255)/256,256,0,stream>>>(degAll, N+MN);
  k_hist2<<<nbE+nbME,256,0,stream>>>(dst, meta_dst, deg, deg_m, E, ME, nbE);
  k_scan1b<<<nb_scan+nb_scan_m,256,0,stream>>>(deg, rowptr, bsum, N, nb_scan,
      deg_m, rowptr_m, bsum_m, MN);
  k_scan2b<<<1,64,0,stream>>>(bsum, nb_scan, rowptr, N, bsum_m, nb_scan_m, rowptr_m, MN);
  k_scan3b<<<nb3B+nb3M,256,0,stream>>>(rowptr, bsum, cursor, N, nb3B,
      rowptr_m, bsum_m, cursor_m, MN);
  k_scatter2<<<nbE+nbME,256,0,stream>>>(dst, src, meta_edge_id, cursor,
      esrc, emeid, E, nbE, meta_dst, meta_src, cursor_m, esrc_m, eorig_m, ME);

  w_repack16<<<8*NB*64,256,0,stream>>>(wptrs, wstage, NB, dflag);

  const int gm = (MN+63)/64;
  const int gN = (N+63)/64;
  const float invNB = 1.0f/(float)NB;

  for (int b=0;b<NB;b++){
    const unsigned short* wq_m = wstage + (size_t)(0*NB+b)*DD*DD;
    const unsigned short* wk_m = wstage + (size_t)(1*NB+b)*DD*DD;
    const unsigned short* wv_m = wstage + (size_t)(2*NB+b)*DD*DD;
    const unsigned short* wo_m = wstage + (size_t)(3*NB+b)*DD*DD;
    const unsigned short* wqb  = wstage + (size_t)(4*NB+b)*DD*DD;
    const unsigned short* wkb  = wstage + (size_t)(5*NB+b)*DD*DD;
    const unsigned short* wvb  = wstage + (size_t)(6*NB+b)*DD*DD;
    const unsigned short* wob  = wstage + (size_t)(7*NB+b)*DD*DD;

    // ---- meta conv (CSR, atomic-free; bf16 exact) ----
    gemm_qkv<EPI_SCALE_CONST,false,false><<<gm,256,0,stream>>>(meta_feat,
        wq_m, wk_m, wv_m, q_m, kf_m, DD, v_m, DD, MN, base_n2, nullptr, nullptr);
    edge_meta_csr<<<(MN+3)/4,256,0,stream>>>(rowptr_m, esrc_m, eorig_m,
        q_m, kf_m, v_m, base, mef, z_m, agg_m, MN);
    gemm128m<EPI_RELU_RES2,true,false,false><<<gm,256,0,stream>>>(agg_m, wo_m,
        meta_out, MN, z_m, nullptr, nullptr, nullptr, nullptr, meta_feat, meta_feat);

    // ---- fused meta learners ----
    learner2<<<MN+ME,128,0,stream>>>(meta_out, mef, MN, u, W2lat, W1lat,
        p2mn, p1mn, w2me, p1me, base, dflag);

    // ---- big conv (fp8 kv) ----
    gemm_qkv<EPI_SCALE_GATHER,true,true><<<gN,256,0,stream>>>(feat, wqb, wkb, wvb,
        q, kv8, 0, kv8 + 128, 0, N, base_n2, p2mn, meta_node_id);
    edge_fused<<<(N+15)/16,256,0,stream>>>(rowptr, esrc, emeid,
        meta_node_id, q, kv8, w2me, p1me, p1mn, base, z, aggb, N);
    gemm128m<EPI_RELU_RES,true,true,true><<<gN,256,0,stream>>>(aggb, wob, feat, N,
        z, nullptr, nullptr, nullptr, feat, nullptr, nullptr);

    // ---- readout (one 16-lane group per target) ----
    readout<<<(BT*16+255)/256,256,0,stream>>>(target_idx, meta_node_id, feat, p1mn,
        base, acc, d_out, (b==NB-1) ? 1 : 0, invNB, BT, dflag);
  }
}